// Round 1
// baseline (1199.764 us; speedup 1.0000x reference)
//
#include <hip/hip_runtime.h>

// CKAFormer R8 (from R7; R7 post-mortem: G gemm still ATOMIC-THROUGHPUT-bound —
// 85G pk-atomics/s at 55.6us with all pipes idle; identical body with plain-store
// epilogue (EPI1) runs >=660 TF vs G's 347 TF):
// - ATOMICS ELIMINATED from both split-K gemms. G: split-K 16->4 (grid 144,
//   K=4096/block), plain bf16 compact tile partials [4][36][128][128] (4.72MB)
//   in a scratch region time-shared with z (z is dead between head_k and next
//   zgemm). PtX: split-K 64->8 (grid 8x8, K=2048/block), plain partials
//   [8][1024][64] (1.05MB) placed in d_out (dead until final head_k).
// - Partials need NO zeroing (each element written exactly once per z) -> big
//   memset dropped; only ssacc (64KB) is zeroed per iter.
// - castgp_k now does the split-K reduction in f32 (4 bufs for G, 8 for PtX),
//   then the proven negate/mirror/swizzle. Fewer bf16 roundings than the old
//   16 chained atomic adds -> absmax should improve or hold.
// - ws total 78,413,824 B < proven 79.1MB footprint.
// - Everything else R7/R5-proven: bf16 ping-pong master, pre-swizzled layouts +
//   global_load_lds 16B staging (0 bank conflicts), fused rownorm, lb(256,3).

#define N_ROWS 16384
#define DIM 1024
#define HID 16
#define OUTD 64
#define DEPTH 6
#define GAMMA 1e-4f

typedef short bf16x8 __attribute__((ext_vector_type(8)));
typedef unsigned short u16x8 __attribute__((ext_vector_type(8)));
typedef float f32x4 __attribute__((ext_vector_type(4)));

#define AS1C(p) ((const __attribute__((address_space(1))) void*)(p))
#define AS3(p)  ((__attribute__((address_space(3))) void*)(p))

__device__ __forceinline__ unsigned short f2bf(float f) {
    unsigned u = __builtin_bit_cast(unsigned, f);
    u += 0x7fffu + ((u >> 16) & 1u);   // round-to-nearest-even
    return (unsigned short)(u >> 16);
}
__device__ __forceinline__ float b2f(ushort u) {
    unsigned x = ((unsigned)u) << 16;
    return __builtin_bit_cast(float, x);
}
// stored offset of logical element n within a swizzled row keyed by (row&7)
__device__ __forceinline__ int swz(int n, int row) {
    return (n & ~63) | ((((n >> 3) & 7) ^ (row & 7)) << 3) | (n & 7);
}

// ---------------------------------------------------------------------------
// Once per launch: master Xm = bf16(X) swizzled rows + rinv[row] = 1/||X[row]||.
__global__ __launch_bounds__(256) void tobf16_k(const float* __restrict__ X,
        ushort* __restrict__ Xm, float* __restrict__ rinv) {
    int row = blockIdx.x, t = threadIdx.x;
    float4 v = ((const float4*)(X + (size_t)row * DIM))[t];
    ushort4 o4;
    o4.x = f2bf(v.x); o4.y = f2bf(v.y); o4.z = f2bf(v.z); o4.w = f2bf(v.w);
    *(ushort4*)(Xm + (size_t)row * DIM + swz(t * 4, row)) = o4;
    float ss = v.x * v.x + v.y * v.y + v.z * v.z + v.w * v.w;
    for (int o = 32; o > 0; o >>= 1) ss += __shfl_down(ss, o);
    __shared__ float wsum[4];
    if ((t & 63) == 0) wsum[t >> 6] = ss;
    __syncthreads();
    if (t == 0) rinv[row] = 1.0f / sqrtf(wsum[0] + wsum[1] + wsum[2] + wsum[3]);
}

// ---------------------------------------------------------------------------
__global__ __launch_bounds__(256) void rsqrt_k(const float* __restrict__ ssacc,
        float* __restrict__ rinv) {
    int i = blockIdx.x * 256 + threadIdx.x;
    rinv[i] = 1.0f / sqrtf(ssacc[i]);
}

// ---------------------------------------------------------------------------
// XnT[d][k] = bf16(Xm[k][d] * rinv[k]), swizzled by d. LDS 64x65 f32 tile.
__global__ __launch_bounds__(256) void transpose_k(const ushort* __restrict__ Xm,
        const float* __restrict__ rinv, ushort* __restrict__ XnT) {
    int r0 = blockIdx.x * 64;   // source row (k) tile
    int c0 = blockIdx.y * 64;   // source col (d) tile
    int t = threadIdx.x;
    __shared__ float ts[64 * 65];
    __shared__ float riS[64];
    if (t < 64) riS[t] = rinv[r0 + t];
    __syncthreads();
#pragma unroll
    for (int i = 0; i < 2; ++i) {
        int idx = i * 256 + t;
        int r = idx >> 3, lg = idx & 7;
        int rr = r0 + r;
        const ushort* p = Xm + (size_t)rr * DIM + c0 + ((lg ^ (rr & 7)) << 3);
        u16x8 a = *(const u16x8*)p;
        float s = riS[r];
        float* d = &ts[r * 65 + lg * 8];
#pragma unroll
        for (int u = 0; u < 8; ++u) d[u] = b2f(a[u]) * s;
    }
    __syncthreads();
#pragma unroll
    for (int i = 0; i < 2; ++i) {
        int g = i * 256 + t;
        int c = g >> 3;
        int rg = g & 7;
        u16x8 pk;
#pragma unroll
        for (int u = 0; u < 8; ++u) pk[u] = f2bf(ts[(rg * 8 + u) * 65 + c]);
        *(u16x8*)(XnT + (size_t)(c0 + c) * N_ROWS + r0 + ((rg ^ (c & 7)) << 3)) = pk;
    }
}

// ---------------------------------------------------------------------------
__global__ __launch_bounds__(256) void prep_w1t_k(const float* __restrict__ W1,
        ushort* __restrict__ W1T) {
    int idx = blockIdx.x * 256 + threadIdx.x;   // 16384
    int h = idx >> 10, j = idx & 1023;
    W1T[idx] = f2bf(W1[j * HID + h]);
}

// ---------------------------------------------------------------------------
// z[m][h] = rv[m] * (Xm[m]·W1[:,h]) + b1[h]   (rv=nullptr -> no scale; final).
__global__ __launch_bounds__(256) void zgemm_k(const ushort* __restrict__ Xm,
        const ushort* __restrict__ W1T, const float* __restrict__ b1,
        float* __restrict__ z, const float* __restrict__ rv) {
    int t = threadIdx.x;
    int wave = t >> 6, lane = t & 63;
    int rl = lane & 15, q = lane >> 4;
    int rowbase = blockIdx.x * 64 + wave * 16;
    int m = rowbase + rl;
    int msw = m & 7;
    const ushort* arow = Xm + (size_t)m * DIM;
    const ushort* brow = W1T + (size_t)rl * DIM + q * 8;
    f32x4 acc = {0.f, 0.f, 0.f, 0.f};
#pragma unroll 8
    for (int kt = 0; kt < DIM; kt += 32) {
        int gl = ((kt >> 3) & 7) | q;
        int off = (kt & ~63) + ((gl ^ msw) << 3);
        bf16x8 a = *(const bf16x8*)(arow + off);
        bf16x8 b = *(const bf16x8*)(brow + kt);
        acc = __builtin_amdgcn_mfma_f32_16x16x32_bf16(a, b, acc, 0, 0, 0);
    }
#pragma unroll
    for (int rg = 0; rg < 4; ++rg) {
        int mm = rowbase + q * 4 + rg;
        float s = rv ? rv[mm] : 1.0f;
        z[(size_t)mm * HID + rl] = acc[rg] * s + b1[rl];
    }
}

// ---------------------------------------------------------------------------
// Per row: h = relu(z); logits = h@W2 + b2; softmax -> Pb (swizzled by m&7)
// + PTb (rows o, swizzled by o&7), or (do_softmax=0) logits f32 to out.
__global__ __launch_bounds__(256) void head_k(const float* __restrict__ z,
        const float* __restrict__ W2, const float* __restrict__ b2,
        ushort* __restrict__ Pb, ushort* __restrict__ PTb,
        float* __restrict__ out, int do_softmax) {
    __shared__ float w2s[HID * OUTD];
    __shared__ float b2s[OUTD];
    int t = threadIdx.x;
    ((float4*)w2s)[t] = ((const float4*)W2)[t];
    if (t < OUTD) b2s[t] = b2[t];
    __syncthreads();
    int m = blockIdx.x * 256 + t;
    float h[HID];
    const float4* zp = (const float4*)(z + (size_t)m * HID);
#pragma unroll
    for (int i = 0; i < 4; ++i) {
        float4 v = zp[i];
        h[i * 4 + 0] = fmaxf(v.x, 0.f); h[i * 4 + 1] = fmaxf(v.y, 0.f);
        h[i * 4 + 2] = fmaxf(v.z, 0.f); h[i * 4 + 3] = fmaxf(v.w, 0.f);
    }
    float lo[OUTD];
#pragma unroll
    for (int o = 0; o < OUTD; ++o) lo[o] = b2s[o];
    for (int i = 0; i < HID; ++i) {
        float hv = h[i];
#pragma unroll
        for (int o = 0; o < OUTD; ++o) lo[o] += hv * w2s[i * OUTD + o];
    }
    if (do_softmax) {
        float mx = lo[0];
#pragma unroll
        for (int o = 1; o < OUTD; ++o) mx = fmaxf(mx, lo[o]);
        float sm = 0.f;
#pragma unroll
        for (int o = 0; o < OUTD; ++o) { float e = __expf(lo[o] - mx); lo[o] = e; sm += e; }
        float inv = 1.0f / sm;
#pragma unroll
        for (int o8 = 0; o8 < 8; ++o8) {
            u16x8 pk;
#pragma unroll
            for (int u = 0; u < 8; ++u) pk[u] = f2bf(lo[o8 * 8 + u] * inv);
            ((u16x8*)(Pb + (size_t)m * OUTD))[o8 ^ (m & 7)] = pk;
        }
#pragma unroll
        for (int o = 0; o < OUTD; ++o)
            PTb[(size_t)o * N_ROWS + swz(m, o)] = f2bf(lo[o] * inv);
    } else {
        float4* op = (float4*)(out + (size_t)m * OUTD);
#pragma unroll
        for (int o4 = 0; o4 < 16; ++o4) {
            float4 v; v.x = lo[o4 * 4 + 0]; v.y = lo[o4 * 4 + 1];
            v.z = lo[o4 * 4 + 2]; v.w = lo[o4 * 4 + 3];
            op[o4] = v;
        }
    }
}

// ---------------------------------------------------------------------------
// Split-K reduction + cast. Gp: [4][36 tiles][128][128] bf16 compact partials;
// PXp: [8][1024][64] bf16 partials. Gb[n][swz] = -sum_z Gp (mirrored upper-tri);
// PtXTb[d][swz] = sum_z PXp.
__global__ __launch_bounds__(256) void castgp_k(const ushort* __restrict__ Gp,
        const ushort* __restrict__ PXp, ushort* __restrict__ Gb,
        ushort* __restrict__ PtXTb) {
    int idx = blockIdx.x * 256 + threadIdx.x;   // 278528 units
    if (idx < 262144) {
        int n = idx >> 8;
        int so = (idx & 255) * 4;
        int k0 = (so & ~63) | ((((so >> 3) & 7) ^ (n & 7)) << 3) | (so & 7);
        ushort po[4];
#pragma unroll
        for (int u = 0; u < 4; ++u) {
            int kk = k0 + u;
            int a = min(n, kk), b = max(n, kk);
            int tm = a >> 7, tn = b >> 7;
            int tlin = tm * 8 - ((tm * (tm - 1)) >> 1) + (tn - tm);
            size_t off = (size_t)tlin * 16384 + (size_t)(a & 127) * 128 + (b & 127);
            float v = 0.f;
#pragma unroll
            for (int zz = 0; zz < 4; ++zz) v += b2f(Gp[(size_t)zz * 589824 + off]);
            po[u] = (ushort)(f2bf(v) ^ 0x8000u);   // negate via sign bit
        }
        ushort4 o; o.x = po[0]; o.y = po[1]; o.z = po[2]; o.w = po[3];
        *(ushort4*)(Gb + (size_t)n * DIM + so) = o;
    } else {
        int vv = idx - 262144;                  // 16384 units
        int d = vv >> 4;
        int so = (vv & 15) * 4;
        int k0 = ((((so >> 3) & 7) ^ (d & 7)) << 3) | (so & 7);
        ushort po[4];
#pragma unroll
        for (int u = 0; u < 4; ++u) {
            float v = 0.f;
#pragma unroll
            for (int zz = 0; zz < 8; ++zz)
                v += b2f(PXp[(size_t)zz * 65536 + (size_t)d * OUTD + k0 + u]);
            po[u] = f2bf(v);
        }
        ushort4 o; o.x = po[0]; o.y = po[1]; o.z = po[2]; o.w = po[3];
        *(ushort4*)(PtXTb + (size_t)d * OUTD + so) = o;
    }
}

// ---------------------------------------------------------------------------
// NT MFMA GEMM (R5-proven body). Non-TRI: m0 = blockIdx.x*BM, n0 = blockIdx.y*BN,
// zidx = blockIdx.z. TRI: flattened grid 36*4; zidx = bid&3 (XCD-friendly
// z-low), tile = bid>>2; upper-triangle 128x128 tiles.
// EPI 0: plain bf16 pair-stores into per-z partial buffer (zidx*pstride elems);
//        TRI uses compact tile addressing, non-TRI uses m*ldc+n.
// EPI 1: seg0 acc scaled by rinv[m]; epilogue writes bf16 master + row
//        sum-of-squares into ssacc.
template<int BM, int BN, int EPI, int TRI>
__global__ __launch_bounds__(256, 3) void gemm_nt_k(
        const ushort* __restrict__ A0, int lda0,
        const ushort* __restrict__ B0, int ldb0, int k0len,
        const ushort* __restrict__ A1, int lda1,
        const ushort* __restrict__ B1, int ldb1, int k1len,
        float* __restrict__ C, int ldc,
        const float* __restrict__ rinv, float gamma,
        float* __restrict__ ssacc, int pstride) {
    constexpr int WTN = BN / 2;
    constexpr int NF = WTN / 16;
    constexpr int NAW = BM / 64;     // waves staging A
    constexpr int NBW = BN / 64;     // waves staging B
    __shared__ ushort ls[(BM + BN) * 64];
    ushort* lsA = ls;
    ushort* lsB = ls + BM * 64;
    int t = threadIdx.x;
    int wave = t >> 6, lane = t & 63;
    int rl = lane & 15, q = lane >> 4;
    int wm = wave & 1, wn = wave >> 1;
    int m0, n0, zidx, tlin = 0;
    if (TRI) {
        int bid = blockIdx.x;            // 36 * 4
        zidx = bid & 3;                  // bid&7 = zidx + 4*(tile&1): one
        tlin = bid >> 2;                 // k-chunk per XCD (L2 affinity)
        int bx = tlin, tm = 0;
        while (bx >= 8 - tm) { bx -= 8 - tm; ++tm; }
        m0 = tm * 128; n0 = (tm + bx) * 128;
    } else {
        m0 = blockIdx.x * BM; n0 = blockIdx.y * BN; zidx = blockIdx.z;
    }
    int lrow8 = lane >> 3, lgrp = lane & 7;
    bool isA = wave < NAW;
    bool active = wave < NAW + NBW;
    int wlocal = isA ? wave : wave - NAW;
    ushort* dstb = ls + (isA ? 0 : BM * 64) + wlocal * 4096;

    f32x4 acc[4][NF];
#pragma unroll
    for (int i = 0; i < 4; ++i)
#pragma unroll
        for (int j = 0; j < NF; ++j) acc[i][j] = f32x4{0.f, 0.f, 0.f, 0.f};
    float rvv[4][4];

    for (int seg = 0; seg < 2; ++seg) {
        int klen = seg ? k1len : k0len;
        if (klen > 0) {
            const ushort* OPA = seg ? A1 : A0;
            const ushort* OPB = seg ? B1 : B0;
            int ldaS = seg ? lda1 : lda0;
            int ldbS = seg ? ldb1 : ldb0;
            int kb = seg ? 0 : zidx * k0len;
            const ushort* srcb;
            size_t ldS;
            if (isA) {
                srcb = OPA + (size_t)(m0 + wlocal * 64 + lrow8) * ldaS + lgrp * 8;
                ldS = (size_t)ldaS;
            } else {
                srcb = OPB + (size_t)(n0 + wlocal * 64 + lrow8) * ldbS + lgrp * 8;
                ldS = (size_t)ldbS;
            }
            srcb += kb;
            for (int kt = 0; kt < klen; kt += 64) {
                if (active) {
#pragma unroll
                    for (int c = 0; c < 8; ++c)
                        __builtin_amdgcn_global_load_lds(AS1C(srcb + c * 8 * ldS),
                                                         AS3(dstb + c * 512), 16, 0, 0);
                    srcb += 64;
                }
                __syncthreads();
#pragma unroll
                for (int s = 0; s < 2; ++s) {
                    bf16x8 af[4], bfr[NF];
#pragma unroll
                    for (int i = 0; i < 4; ++i) {
                        int row = wm * 64 + i * 16 + rl;
                        int sg = ((s << 2) | q) ^ (row & 7);
                        af[i] = *(const bf16x8*)&lsA[row * 64 + sg * 8];
                    }
#pragma unroll
                    for (int j = 0; j < NF; ++j) {
                        int row = wn * WTN + j * 16 + rl;
                        int sg = ((s << 2) | q) ^ (row & 7);
                        bfr[j] = *(const bf16x8*)&lsB[row * 64 + sg * 8];
                    }
#pragma unroll
                    for (int i = 0; i < 4; ++i)
#pragma unroll
                        for (int j = 0; j < NF; ++j)
                            acc[i][j] = __builtin_amdgcn_mfma_f32_16x16x32_bf16(
                                af[i], bfr[j], acc[i][j], 0, 0, 0);
                }
                __syncthreads();
            }
        }
        if (EPI == 1 && seg == 0) {
#pragma unroll
            for (int i = 0; i < 4; ++i)
#pragma unroll
                for (int rg = 0; rg < 4; ++rg)
                    rvv[i][rg] = rinv[m0 + wm * 64 + i * 16 + q * 4 + rg];
#pragma unroll
            for (int i = 0; i < 4; ++i)
#pragma unroll
                for (int j = 0; j < NF; ++j)
#pragma unroll
                    for (int rg = 0; rg < 4; ++rg)
                        acc[i][j][rg] *= rvv[i][rg];
        }
    }

    if (EPI == 0) {
        // plain bf16 pair stores into this z-slice's partial buffer
        ushort* Cb = (ushort*)C + (size_t)zidx * (size_t)pstride;
#pragma unroll
        for (int i = 0; i < 4; ++i)
#pragma unroll
            for (int j = 0; j < NF; ++j)
#pragma unroll
                for (int rg = 0; rg < 4; ++rg) {
                    float v = acc[i][j][rg];
                    float vp = __shfl_xor(v, 1);   // partner lane's (n^1) value
                    if ((rl & 1) == 0) {
                        int ml = wm * 64 + i * 16 + q * 4 + rg;
                        int nl = wn * WTN + j * 16 + rl;
                        size_t off;
                        if (TRI)
                            off = (size_t)tlin * (BM * BN) + (size_t)ml * BN + nl;
                        else
                            off = (size_t)(m0 + ml) * ldc + (n0 + nl);
                        unsigned pk = (unsigned)f2bf(v) | ((unsigned)f2bf(vp) << 16);
                        *(unsigned*)(Cb + off) = pk;
                    }
                }
    } else {
#pragma unroll
        for (int i = 0; i < 4; ++i)
#pragma unroll
            for (int rg = 0; rg < 4; ++rg) {
                int m = m0 + wm * 64 + i * 16 + q * 4 + rg;
                float ssl = 0.f;
#pragma unroll
                for (int j = 0; j < NF; ++j) {
                    int n = n0 + wn * WTN + j * 16 + rl;
                    int so = swz(n, m);
                    float base = b2f(A0[(size_t)m * lda0 + so]);
                    float vf = base * rvv[i][rg] + gamma * acc[i][j][rg];
                    ((ushort*)C)[(size_t)m * ldc + so] = f2bf(vf);
                    ssl += vf * vf;
                }
                ssl += __shfl_xor(ssl, 1);
                ssl += __shfl_xor(ssl, 2);
                ssl += __shfl_xor(ssl, 4);
                ssl += __shfl_xor(ssl, 8);
                if (rl == 0) atomicAdd(&ssacc[m], ssl);
            }
    }
}

// ---------------------------------------------------------------------------
extern "C" void kernel_launch(void* const* d_in, const int* in_sizes, int n_in,
                              void* d_out, int out_size, void* d_ws, size_t ws_size,
                              hipStream_t stream) {
    const float* X = (const float*)d_in[0];
    const float* W1 = (const float*)d_in[1];
    const float* b1 = (const float*)d_in[2];
    const float* W2 = (const float*)d_in[3];
    const float* b2 = (const float*)d_in[4];
    float* out = (float*)d_out;
    char* ws = (char*)d_ws;

    constexpr size_t O_BufA    = 0;                                     // 33,554,432
    constexpr size_t O_BufB    = O_BufA + (size_t)N_ROWS * DIM * 2;     // 33,554,432
    constexpr size_t O_Pb      = O_BufB + (size_t)N_ROWS * DIM * 2;     //  2,097,152
    constexpr size_t O_PTb     = O_Pb + (size_t)N_ROWS * OUTD * 2;      //  2,097,152
    constexpr size_t O_Gb      = O_PTb + (size_t)OUTD * N_ROWS * 2;     //  2,097,152
    constexpr size_t O_PtXTb   = O_Gb + (size_t)DIM * DIM * 2;          //    131,072
    constexpr size_t O_riv     = O_PtXTb + (size_t)DIM * OUTD * 2;      //     65,536
    constexpr size_t O_W1T     = O_riv + (size_t)N_ROWS * 4;            //     32,768
    constexpr size_t O_ssacc   = O_W1T + (size_t)HID * DIM * 2;         //     65,536
    constexpr size_t O_scratch = O_ssacc + (size_t)N_ROWS * 4;          //  4,718,592
    // scratch time-shares: z (1,048,576 f32, live zgemm->head) and Gpart
    // (4 x 36 x 16384 bf16 = 4,718,592, live Ggemm->castgp). PXpart (1,048,576)
    // lives in d_out (4 MB, dead until final head_k).
    // total ws = 78,413,824 B — under the proven 79.1 MB footprint

    ushort* bufA  = (ushort*)(ws + O_BufA);
    ushort* bufB  = (ushort*)(ws + O_BufB);
    ushort* Pb    = (ushort*)(ws + O_Pb);
    ushort* PTb   = (ushort*)(ws + O_PTb);
    ushort* Gb    = (ushort*)(ws + O_Gb);
    ushort* PtXTb = (ushort*)(ws + O_PtXTb);
    float*  riv   = (float*)(ws + O_riv);
    ushort* W1T   = (ushort*)(ws + O_W1T);
    float*  ssacc = (float*)(ws + O_ssacc);
    float*  z     = (float*)(ws + O_scratch);
    ushort* Gpart = (ushort*)(ws + O_scratch);
    ushort* PXpart = (ushort*)d_out;
    (void)in_sizes; (void)n_in; (void)out_size; (void)ws_size;

    prep_w1t_k<<<64, 256, 0, stream>>>(W1, W1T);
    tobf16_k<<<N_ROWS, 256, 0, stream>>>(X, bufA, riv);

    ushort* xm  = bufA;   // current master X_t (bf16, swizzled rows)
    ushort* alt = bufB;   // scratch: XnT during iter, then becomes X_{t+1}

    for (int it = 0; it < DEPTH; ++it) {
        transpose_k<<<dim3(N_ROWS / 64, DIM / 64), 256, 0, stream>>>(xm, riv, alt);
        zgemm_k<<<N_ROWS / 64, 256, 0, stream>>>(xm, W1T, b1, z, riv);
        head_k<<<N_ROWS / 256, 256, 0, stream>>>(z, W2, b2, Pb, PTb, nullptr, 1);
        // G = XnT . XnT^T : 36 upper-tri tiles x split-K 4, plain partials
        // (no atomics, no zeroing needed; clobbers z, which is dead now)
        gemm_nt_k<128, 128, 0, 1><<<dim3(36 * 4, 1, 1), 256, 0, stream>>>(
            alt, N_ROWS, alt, N_ROWS, 4096,
            nullptr, 0, nullptr, 0, 0,
            (float*)Gpart, 128, nullptr, 0.f, nullptr, 36 * 16384);
        // PtX^T[d][o] = XnT . PTb^T : split-K 8, plain partials in d_out
        gemm_nt_k<128, 64, 0, 0><<<dim3(8, 1, 8), 256, 0, stream>>>(
            alt, N_ROWS, PTb, N_ROWS, 2048,
            nullptr, 0, nullptr, 0, 0,
            (float*)PXpart, OUTD, nullptr, 0.f, nullptr, DIM * OUTD);
        castgp_k<<<1088, 256, 0, stream>>>(Gpart, PXpart, Gb, PtXTb);
        hipMemsetAsync(ws + O_ssacc, 0, (size_t)N_ROWS * 4, stream);
        // X_{t+1} = Xn + g*(P@PtX - Xn@G); writes `alt`; accumulates ssacc
        gemm_nt_k<128, 128, 1, 0><<<dim3(N_ROWS / 128, DIM / 128, 1), 256, 0, stream>>>(
            xm, DIM, Gb, DIM, 1024,
            Pb, OUTD, PtXTb, OUTD, OUTD,
            (float*)alt, DIM, riv, GAMMA, ssacc, 0);
        rsqrt_k<<<N_ROWS / 256, 256, 0, stream>>>(ssacc, riv);
        ushort* tmp = xm; xm = alt; alt = tmp;   // ping-pong
    }

    // final: out = relu(X@W1 + b1) @ W2 + b2  (unnormalized master, rv=nullptr)
    zgemm_k<<<N_ROWS / 64, 256, 0, stream>>>(xm, W1T, b1, z, nullptr);
    head_k<<<N_ROWS / 256, 256, 0, stream>>>(z, W2, b2, Pb, PTb, out, 0);
}

// Round 2
// 1148.146 us; speedup vs baseline: 1.0450x; 1.0450x over previous
//
#include <hip/hip_runtime.h>

// CKAFormer R9 (from R8; R8 post-mortem: plain-store partials fixed the atomic
// bound (WRITE 18.4->4.6MB) but split-K 16->4 cratered parallelism: 144 blocks,
// Occupancy 22->5.8%, G gemm 55.6->66.7us, FETCH doubled since R7's XCD
// z-affinity was dropped. PtX at 64 blocks regressed likewise):
// - DUAL PATH on runtime ws_size. Big path (ws_size >= 92.6MB): G split-K 16
//   restored on R7's exact flattened 8*36*2 grid (z-low in bid&7 -> per-XCD
//   2MB k-chunk L2 affinity, FETCH 16.5MB proven) but with R8's zero-atomic
//   plain bf16 compact-tile partial stores ([16][36][128][128] = 18.9MB at
//   O_scratch). PtX split-K 32, partials exactly fill d_out (4MB), grid 256.
// - Small path (fallback, correctness-proven R8 config): G split-K 4 in the
//   4.7MB scratch, PtX split-K 8 in d_out.
// - castgp_k takes runtime (nzg, nzp) and f32-reduces either way.
// - Everything else R8/R5-proven: bf16 ping-pong master, pre-swizzled layouts +
//   global_load_lds 16B staging (0 bank conflicts), fused rownorm, lb(256,3).

#define N_ROWS 16384
#define DIM 1024
#define HID 16
#define OUTD 64
#define DEPTH 6
#define GAMMA 1e-4f

typedef short bf16x8 __attribute__((ext_vector_type(8)));
typedef unsigned short u16x8 __attribute__((ext_vector_type(8)));
typedef float f32x4 __attribute__((ext_vector_type(4)));

#define AS1C(p) ((const __attribute__((address_space(1))) void*)(p))
#define AS3(p)  ((__attribute__((address_space(3))) void*)(p))

__device__ __forceinline__ unsigned short f2bf(float f) {
    unsigned u = __builtin_bit_cast(unsigned, f);
    u += 0x7fffu + ((u >> 16) & 1u);   // round-to-nearest-even
    return (unsigned short)(u >> 16);
}
__device__ __forceinline__ float b2f(ushort u) {
    unsigned x = ((unsigned)u) << 16;
    return __builtin_bit_cast(float, x);
}
// stored offset of logical element n within a swizzled row keyed by (row&7)
__device__ __forceinline__ int swz(int n, int row) {
    return (n & ~63) | ((((n >> 3) & 7) ^ (row & 7)) << 3) | (n & 7);
}

// ---------------------------------------------------------------------------
// Once per launch: master Xm = bf16(X) swizzled rows + rinv[row] = 1/||X[row]||.
__global__ __launch_bounds__(256) void tobf16_k(const float* __restrict__ X,
        ushort* __restrict__ Xm, float* __restrict__ rinv) {
    int row = blockIdx.x, t = threadIdx.x;
    float4 v = ((const float4*)(X + (size_t)row * DIM))[t];
    ushort4 o4;
    o4.x = f2bf(v.x); o4.y = f2bf(v.y); o4.z = f2bf(v.z); o4.w = f2bf(v.w);
    *(ushort4*)(Xm + (size_t)row * DIM + swz(t * 4, row)) = o4;
    float ss = v.x * v.x + v.y * v.y + v.z * v.z + v.w * v.w;
    for (int o = 32; o > 0; o >>= 1) ss += __shfl_down(ss, o);
    __shared__ float wsum[4];
    if ((t & 63) == 0) wsum[t >> 6] = ss;
    __syncthreads();
    if (t == 0) rinv[row] = 1.0f / sqrtf(wsum[0] + wsum[1] + wsum[2] + wsum[3]);
}

// ---------------------------------------------------------------------------
__global__ __launch_bounds__(256) void rsqrt_k(const float* __restrict__ ssacc,
        float* __restrict__ rinv) {
    int i = blockIdx.x * 256 + threadIdx.x;
    rinv[i] = 1.0f / sqrtf(ssacc[i]);
}

// ---------------------------------------------------------------------------
// XnT[d][k] = bf16(Xm[k][d] * rinv[k]), swizzled by d. LDS 64x65 f32 tile.
__global__ __launch_bounds__(256) void transpose_k(const ushort* __restrict__ Xm,
        const float* __restrict__ rinv, ushort* __restrict__ XnT) {
    int r0 = blockIdx.x * 64;   // source row (k) tile
    int c0 = blockIdx.y * 64;   // source col (d) tile
    int t = threadIdx.x;
    __shared__ float ts[64 * 65];
    __shared__ float riS[64];
    if (t < 64) riS[t] = rinv[r0 + t];
    __syncthreads();
#pragma unroll
    for (int i = 0; i < 2; ++i) {
        int idx = i * 256 + t;
        int r = idx >> 3, lg = idx & 7;
        int rr = r0 + r;
        const ushort* p = Xm + (size_t)rr * DIM + c0 + ((lg ^ (rr & 7)) << 3);
        u16x8 a = *(const u16x8*)p;
        float s = riS[r];
        float* d = &ts[r * 65 + lg * 8];
#pragma unroll
        for (int u = 0; u < 8; ++u) d[u] = b2f(a[u]) * s;
    }
    __syncthreads();
#pragma unroll
    for (int i = 0; i < 2; ++i) {
        int g = i * 256 + t;
        int c = g >> 3;
        int rg = g & 7;
        u16x8 pk;
#pragma unroll
        for (int u = 0; u < 8; ++u) pk[u] = f2bf(ts[(rg * 8 + u) * 65 + c]);
        *(u16x8*)(XnT + (size_t)(c0 + c) * N_ROWS + r0 + ((rg ^ (c & 7)) << 3)) = pk;
    }
}

// ---------------------------------------------------------------------------
__global__ __launch_bounds__(256) void prep_w1t_k(const float* __restrict__ W1,
        ushort* __restrict__ W1T) {
    int idx = blockIdx.x * 256 + threadIdx.x;   // 16384
    int h = idx >> 10, j = idx & 1023;
    W1T[idx] = f2bf(W1[j * HID + h]);
}

// ---------------------------------------------------------------------------
// z[m][h] = rv[m] * (Xm[m]·W1[:,h]) + b1[h]   (rv=nullptr -> no scale; final).
__global__ __launch_bounds__(256) void zgemm_k(const ushort* __restrict__ Xm,
        const ushort* __restrict__ W1T, const float* __restrict__ b1,
        float* __restrict__ z, const float* __restrict__ rv) {
    int t = threadIdx.x;
    int wave = t >> 6, lane = t & 63;
    int rl = lane & 15, q = lane >> 4;
    int rowbase = blockIdx.x * 64 + wave * 16;
    int m = rowbase + rl;
    int msw = m & 7;
    const ushort* arow = Xm + (size_t)m * DIM;
    const ushort* brow = W1T + (size_t)rl * DIM + q * 8;
    f32x4 acc = {0.f, 0.f, 0.f, 0.f};
#pragma unroll 8
    for (int kt = 0; kt < DIM; kt += 32) {
        int gl = ((kt >> 3) & 7) | q;
        int off = (kt & ~63) + ((gl ^ msw) << 3);
        bf16x8 a = *(const bf16x8*)(arow + off);
        bf16x8 b = *(const bf16x8*)(brow + kt);
        acc = __builtin_amdgcn_mfma_f32_16x16x32_bf16(a, b, acc, 0, 0, 0);
    }
#pragma unroll
    for (int rg = 0; rg < 4; ++rg) {
        int mm = rowbase + q * 4 + rg;
        float s = rv ? rv[mm] : 1.0f;
        z[(size_t)mm * HID + rl] = acc[rg] * s + b1[rl];
    }
}

// ---------------------------------------------------------------------------
// Per row: h = relu(z); logits = h@W2 + b2; softmax -> Pb (swizzled by m&7)
// + PTb (rows o, swizzled by o&7), or (do_softmax=0) logits f32 to out.
__global__ __launch_bounds__(256) void head_k(const float* __restrict__ z,
        const float* __restrict__ W2, const float* __restrict__ b2,
        ushort* __restrict__ Pb, ushort* __restrict__ PTb,
        float* __restrict__ out, int do_softmax) {
    __shared__ float w2s[HID * OUTD];
    __shared__ float b2s[OUTD];
    int t = threadIdx.x;
    ((float4*)w2s)[t] = ((const float4*)W2)[t];
    if (t < OUTD) b2s[t] = b2[t];
    __syncthreads();
    int m = blockIdx.x * 256 + t;
    float h[HID];
    const float4* zp = (const float4*)(z + (size_t)m * HID);
#pragma unroll
    for (int i = 0; i < 4; ++i) {
        float4 v = zp[i];
        h[i * 4 + 0] = fmaxf(v.x, 0.f); h[i * 4 + 1] = fmaxf(v.y, 0.f);
        h[i * 4 + 2] = fmaxf(v.z, 0.f); h[i * 4 + 3] = fmaxf(v.w, 0.f);
    }
    float lo[OUTD];
#pragma unroll
    for (int o = 0; o < OUTD; ++o) lo[o] = b2s[o];
    for (int i = 0; i < HID; ++i) {
        float hv = h[i];
#pragma unroll
        for (int o = 0; o < OUTD; ++o) lo[o] += hv * w2s[i * OUTD + o];
    }
    if (do_softmax) {
        float mx = lo[0];
#pragma unroll
        for (int o = 1; o < OUTD; ++o) mx = fmaxf(mx, lo[o]);
        float sm = 0.f;
#pragma unroll
        for (int o = 0; o < OUTD; ++o) { float e = __expf(lo[o] - mx); lo[o] = e; sm += e; }
        float inv = 1.0f / sm;
#pragma unroll
        for (int o8 = 0; o8 < 8; ++o8) {
            u16x8 pk;
#pragma unroll
            for (int u = 0; u < 8; ++u) pk[u] = f2bf(lo[o8 * 8 + u] * inv);
            ((u16x8*)(Pb + (size_t)m * OUTD))[o8 ^ (m & 7)] = pk;
        }
#pragma unroll
        for (int o = 0; o < OUTD; ++o)
            PTb[(size_t)o * N_ROWS + swz(m, o)] = f2bf(lo[o] * inv);
    } else {
        float4* op = (float4*)(out + (size_t)m * OUTD);
#pragma unroll
        for (int o4 = 0; o4 < 16; ++o4) {
            float4 v; v.x = lo[o4 * 4 + 0]; v.y = lo[o4 * 4 + 1];
            v.z = lo[o4 * 4 + 2]; v.w = lo[o4 * 4 + 3];
            op[o4] = v;
        }
    }
}

// ---------------------------------------------------------------------------
// Split-K reduction + cast, runtime z-counts. Gp: [nzg][36 tiles][128][128]
// bf16 compact partials; PXp: [nzp][1024][64] bf16 partials.
// Gb[n][swz] = -sum_z Gp (mirrored upper-tri); PtXTb[d][swz] = sum_z PXp.
__global__ __launch_bounds__(256) void castgp_k(const ushort* __restrict__ Gp,
        const ushort* __restrict__ PXp, ushort* __restrict__ Gb,
        ushort* __restrict__ PtXTb, int nzg, int nzp) {
    int idx = blockIdx.x * 256 + threadIdx.x;   // 278528 units
    if (idx < 262144) {
        int n = idx >> 8;
        int so = (idx & 255) * 4;
        int k0 = (so & ~63) | ((((so >> 3) & 7) ^ (n & 7)) << 3) | (so & 7);
        ushort po[4];
#pragma unroll
        for (int u = 0; u < 4; ++u) {
            int kk = k0 + u;
            int a = min(n, kk), b = max(n, kk);
            int tm = a >> 7, tn = b >> 7;
            int tlin = tm * 8 - ((tm * (tm - 1)) >> 1) + (tn - tm);
            size_t off = (size_t)tlin * 16384 + (size_t)(a & 127) * 128 + (b & 127);
            float v = 0.f;
            for (int zz = 0; zz < nzg; ++zz) v += b2f(Gp[(size_t)zz * 589824 + off]);
            po[u] = (ushort)(f2bf(v) ^ 0x8000u);   // negate via sign bit
        }
        ushort4 o; o.x = po[0]; o.y = po[1]; o.z = po[2]; o.w = po[3];
        *(ushort4*)(Gb + (size_t)n * DIM + so) = o;
    } else {
        int vv = idx - 262144;                  // 16384 units
        int d = vv >> 4;
        int so = (vv & 15) * 4;
        int k0 = ((((so >> 3) & 7) ^ (d & 7)) << 3) | (so & 7);
        ushort po[4];
#pragma unroll
        for (int u = 0; u < 4; ++u) {
            float v = 0.f;
            for (int zz = 0; zz < nzp; ++zz)
                v += b2f(PXp[(size_t)zz * 65536 + (size_t)d * OUTD + k0 + u]);
            po[u] = f2bf(v);
        }
        ushort4 o; o.x = po[0]; o.y = po[1]; o.z = po[2]; o.w = po[3];
        *(ushort4*)(PtXTb + (size_t)d * OUTD + so) = o;
    }
}

// ---------------------------------------------------------------------------
// NT MFMA GEMM (R5-proven body). Non-TRI: m0 = blockIdx.x*BM, n0 = blockIdx.y*BN,
// zidx = blockIdx.z. TRI: flattened grid; nz==16 -> R7 mapping (grid 8*36*2,
// zidx = (bid&7)|(zhi<<3), z-low on XCD for L2 k-chunk affinity); nz==4 ->
// grid 36*4, zidx = bid&3. Upper-triangle 128x128 tiles.
// EPI 0: plain bf16 pair-stores into per-z partial buffer (zidx*pstride elems);
//        TRI uses compact tile addressing, non-TRI uses m*ldc+n.
// EPI 1: seg0 acc scaled by rinv[m]; epilogue writes bf16 master + row
//        sum-of-squares into ssacc.
template<int BM, int BN, int EPI, int TRI>
__global__ __launch_bounds__(256, 3) void gemm_nt_k(
        const ushort* __restrict__ A0, int lda0,
        const ushort* __restrict__ B0, int ldb0, int k0len,
        const ushort* __restrict__ A1, int lda1,
        const ushort* __restrict__ B1, int ldb1, int k1len,
        float* __restrict__ C, int ldc,
        const float* __restrict__ rinv, float gamma,
        float* __restrict__ ssacc, int pstride, int nz) {
    constexpr int WTN = BN / 2;
    constexpr int NF = WTN / 16;
    constexpr int NAW = BM / 64;     // waves staging A
    constexpr int NBW = BN / 64;     // waves staging B
    __shared__ ushort ls[(BM + BN) * 64];
    ushort* lsA = ls;
    ushort* lsB = ls + BM * 64;
    int t = threadIdx.x;
    int wave = t >> 6, lane = t & 63;
    int rl = lane & 15, q = lane >> 4;
    int wm = wave & 1, wn = wave >> 1;
    int m0, n0, zidx, tlin = 0;
    if (TRI) {
        int bid = blockIdx.x;
        int bx, tm = 0;
        if (nz == 16) {                 // R7-proven mapping: grid 8*36*2
            int rest = bid >> 3;
            bx = rest % 36;
            int zhi = rest / 36;
            zidx = (bid & 7) | (zhi << 3);
        } else {                        // fallback: grid 36*4
            zidx = bid & 3;
            bx = bid >> 2;
        }
        tlin = bx;
        while (bx >= 8 - tm) { bx -= 8 - tm; ++tm; }
        m0 = tm * 128; n0 = (tm + bx) * 128;
    } else {
        m0 = blockIdx.x * BM; n0 = blockIdx.y * BN; zidx = blockIdx.z;
    }
    int lrow8 = lane >> 3, lgrp = lane & 7;
    bool isA = wave < NAW;
    bool active = wave < NAW + NBW;
    int wlocal = isA ? wave : wave - NAW;
    ushort* dstb = ls + (isA ? 0 : BM * 64) + wlocal * 4096;

    f32x4 acc[4][NF];
#pragma unroll
    for (int i = 0; i < 4; ++i)
#pragma unroll
        for (int j = 0; j < NF; ++j) acc[i][j] = f32x4{0.f, 0.f, 0.f, 0.f};
    float rvv[4][4];

    for (int seg = 0; seg < 2; ++seg) {
        int klen = seg ? k1len : k0len;
        if (klen > 0) {
            const ushort* OPA = seg ? A1 : A0;
            const ushort* OPB = seg ? B1 : B0;
            int ldaS = seg ? lda1 : lda0;
            int ldbS = seg ? ldb1 : ldb0;
            int kb = seg ? 0 : zidx * k0len;
            const ushort* srcb;
            size_t ldS;
            if (isA) {
                srcb = OPA + (size_t)(m0 + wlocal * 64 + lrow8) * ldaS + lgrp * 8;
                ldS = (size_t)ldaS;
            } else {
                srcb = OPB + (size_t)(n0 + wlocal * 64 + lrow8) * ldbS + lgrp * 8;
                ldS = (size_t)ldbS;
            }
            srcb += kb;
            for (int kt = 0; kt < klen; kt += 64) {
                if (active) {
#pragma unroll
                    for (int c = 0; c < 8; ++c)
                        __builtin_amdgcn_global_load_lds(AS1C(srcb + c * 8 * ldS),
                                                         AS3(dstb + c * 512), 16, 0, 0);
                    srcb += 64;
                }
                __syncthreads();
#pragma unroll
                for (int s = 0; s < 2; ++s) {
                    bf16x8 af[4], bfr[NF];
#pragma unroll
                    for (int i = 0; i < 4; ++i) {
                        int row = wm * 64 + i * 16 + rl;
                        int sg = ((s << 2) | q) ^ (row & 7);
                        af[i] = *(const bf16x8*)&lsA[row * 64 + sg * 8];
                    }
#pragma unroll
                    for (int j = 0; j < NF; ++j) {
                        int row = wn * WTN + j * 16 + rl;
                        int sg = ((s << 2) | q) ^ (row & 7);
                        bfr[j] = *(const bf16x8*)&lsB[row * 64 + sg * 8];
                    }
#pragma unroll
                    for (int i = 0; i < 4; ++i)
#pragma unroll
                        for (int j = 0; j < NF; ++j)
                            acc[i][j] = __builtin_amdgcn_mfma_f32_16x16x32_bf16(
                                af[i], bfr[j], acc[i][j], 0, 0, 0);
                }
                __syncthreads();
            }
        }
        if (EPI == 1 && seg == 0) {
#pragma unroll
            for (int i = 0; i < 4; ++i)
#pragma unroll
                for (int rg = 0; rg < 4; ++rg)
                    rvv[i][rg] = rinv[m0 + wm * 64 + i * 16 + q * 4 + rg];
#pragma unroll
            for (int i = 0; i < 4; ++i)
#pragma unroll
                for (int j = 0; j < NF; ++j)
#pragma unroll
                    for (int rg = 0; rg < 4; ++rg)
                        acc[i][j][rg] *= rvv[i][rg];
        }
    }

    if (EPI == 0) {
        // plain bf16 pair stores into this z-slice's partial buffer
        ushort* Cb = (ushort*)C + (size_t)zidx * (size_t)pstride;
#pragma unroll
        for (int i = 0; i < 4; ++i)
#pragma unroll
            for (int j = 0; j < NF; ++j)
#pragma unroll
                for (int rg = 0; rg < 4; ++rg) {
                    float v = acc[i][j][rg];
                    float vp = __shfl_xor(v, 1);   // partner lane's (n^1) value
                    if ((rl & 1) == 0) {
                        int ml = wm * 64 + i * 16 + q * 4 + rg;
                        int nl = wn * WTN + j * 16 + rl;
                        size_t off;
                        if (TRI)
                            off = (size_t)tlin * (BM * BN) + (size_t)ml * BN + nl;
                        else
                            off = (size_t)(m0 + ml) * ldc + (n0 + nl);
                        unsigned pk = (unsigned)f2bf(v) | ((unsigned)f2bf(vp) << 16);
                        *(unsigned*)(Cb + off) = pk;
                    }
                }
    } else {
#pragma unroll
        for (int i = 0; i < 4; ++i)
#pragma unroll
            for (int rg = 0; rg < 4; ++rg) {
                int m = m0 + wm * 64 + i * 16 + q * 4 + rg;
                float ssl = 0.f;
#pragma unroll
                for (int j = 0; j < NF; ++j) {
                    int n = n0 + wn * WTN + j * 16 + rl;
                    int so = swz(n, m);
                    float base = b2f(A0[(size_t)m * lda0 + so]);
                    float vf = base * rvv[i][rg] + gamma * acc[i][j][rg];
                    ((ushort*)C)[(size_t)m * ldc + so] = f2bf(vf);
                    ssl += vf * vf;
                }
                ssl += __shfl_xor(ssl, 1);
                ssl += __shfl_xor(ssl, 2);
                ssl += __shfl_xor(ssl, 4);
                ssl += __shfl_xor(ssl, 8);
                if (rl == 0) atomicAdd(&ssacc[m], ssl);
            }
    }
}

// ---------------------------------------------------------------------------
extern "C" void kernel_launch(void* const* d_in, const int* in_sizes, int n_in,
                              void* d_out, int out_size, void* d_ws, size_t ws_size,
                              hipStream_t stream) {
    const float* X = (const float*)d_in[0];
    const float* W1 = (const float*)d_in[1];
    const float* b1 = (const float*)d_in[2];
    const float* W2 = (const float*)d_in[3];
    const float* b2 = (const float*)d_in[4];
    float* out = (float*)d_out;
    char* ws = (char*)d_ws;

    constexpr size_t O_BufA    = 0;                                     // 33,554,432
    constexpr size_t O_BufB    = O_BufA + (size_t)N_ROWS * DIM * 2;     // 33,554,432
    constexpr size_t O_Pb      = O_BufB + (size_t)N_ROWS * DIM * 2;     //  2,097,152
    constexpr size_t O_PTb     = O_Pb + (size_t)N_ROWS * OUTD * 2;      //  2,097,152
    constexpr size_t O_Gb      = O_PTb + (size_t)OUTD * N_ROWS * 2;     //  2,097,152
    constexpr size_t O_PtXTb   = O_Gb + (size_t)DIM * DIM * 2;          //    131,072
    constexpr size_t O_riv     = O_PtXTb + (size_t)DIM * OUTD * 2;      //     65,536
    constexpr size_t O_W1T     = O_riv + (size_t)N_ROWS * 4;            //     32,768
    constexpr size_t O_ssacc   = O_W1T + (size_t)HID * DIM * 2;         //     65,536
    constexpr size_t O_scratch = O_ssacc + (size_t)N_ROWS * 4;          // = 73,695,232
    // scratch time-shares: z (1,048,576 f32, live zgemm->head) and Gpart
    // (big: 16 x 589824 x 2 = 18,874,368 -> ws end 92,569,600;
    //  small: 4 x 589824 x 2 = 4,718,592 -> ws end 78,413,824).
    // PXpart lives in d_out (4MB, dead until final head_k):
    //  big: 32 x 65536 x 2 = 4,194,304 (exact fit); small: 8 z = 1,048,576.
    constexpr size_t WS_BIG = O_scratch + (size_t)16 * 589824 * 2;

    ushort* bufA  = (ushort*)(ws + O_BufA);
    ushort* bufB  = (ushort*)(ws + O_BufB);
    ushort* Pb    = (ushort*)(ws + O_Pb);
    ushort* PTb   = (ushort*)(ws + O_PTb);
    ushort* Gb    = (ushort*)(ws + O_Gb);
    ushort* PtXTb = (ushort*)(ws + O_PtXTb);
    float*  riv   = (float*)(ws + O_riv);
    ushort* W1T   = (ushort*)(ws + O_W1T);
    float*  ssacc = (float*)(ws + O_ssacc);
    float*  z     = (float*)(ws + O_scratch);
    ushort* Gpart = (ushort*)(ws + O_scratch);
    ushort* PXpart = (ushort*)d_out;
    (void)in_sizes; (void)n_in; (void)out_size;

    const bool big = ws_size >= WS_BIG;

    prep_w1t_k<<<64, 256, 0, stream>>>(W1, W1T);
    tobf16_k<<<N_ROWS, 256, 0, stream>>>(X, bufA, riv);

    ushort* xm  = bufA;   // current master X_t (bf16, swizzled rows)
    ushort* alt = bufB;   // scratch: XnT during iter, then becomes X_{t+1}

    for (int it = 0; it < DEPTH; ++it) {
        transpose_k<<<dim3(N_ROWS / 64, DIM / 64), 256, 0, stream>>>(xm, riv, alt);
        zgemm_k<<<N_ROWS / 64, 256, 0, stream>>>(xm, W1T, b1, z, riv);
        head_k<<<N_ROWS / 256, 256, 0, stream>>>(z, W2, b2, Pb, PTb, nullptr, 1);
        if (big) {
            // G = XnT . XnT^T : 36 upper-tri tiles x split-K 16 on R7's
            // XCD-affine flattened grid; plain partials (clobbers dead z)
            gemm_nt_k<128, 128, 0, 1><<<dim3(8 * 36 * 2, 1, 1), 256, 0, stream>>>(
                alt, N_ROWS, alt, N_ROWS, 1024,
                nullptr, 0, nullptr, 0, 0,
                (float*)Gpart, 128, nullptr, 0.f, nullptr, 36 * 16384, 16);
            // PtX^T[d][o] = XnT . PTb^T : split-K 32, partials fill d_out
            gemm_nt_k<128, 64, 0, 0><<<dim3(8, 1, 32), 256, 0, stream>>>(
                alt, N_ROWS, PTb, N_ROWS, 512,
                nullptr, 0, nullptr, 0, 0,
                (float*)PXpart, OUTD, nullptr, 0.f, nullptr, DIM * OUTD, 0);
            castgp_k<<<1088, 256, 0, stream>>>(Gpart, PXpart, Gb, PtXTb, 16, 32);
        } else {
            gemm_nt_k<128, 128, 0, 1><<<dim3(36 * 4, 1, 1), 256, 0, stream>>>(
                alt, N_ROWS, alt, N_ROWS, 4096,
                nullptr, 0, nullptr, 0, 0,
                (float*)Gpart, 128, nullptr, 0.f, nullptr, 36 * 16384, 4);
            gemm_nt_k<128, 64, 0, 0><<<dim3(8, 1, 8), 256, 0, stream>>>(
                alt, N_ROWS, PTb, N_ROWS, 2048,
                nullptr, 0, nullptr, 0, 0,
                (float*)PXpart, OUTD, nullptr, 0.f, nullptr, DIM * OUTD, 0);
            castgp_k<<<1088, 256, 0, stream>>>(Gpart, PXpart, Gb, PtXTb, 4, 8);
        }
        hipMemsetAsync(ws + O_ssacc, 0, (size_t)N_ROWS * 4, stream);
        // X_{t+1} = Xn + g*(P@PtX - Xn@G); writes `alt`; accumulates ssacc
        gemm_nt_k<128, 128, 1, 0><<<dim3(N_ROWS / 128, DIM / 128, 1), 256, 0, stream>>>(
            xm, DIM, Gb, DIM, 1024,
            Pb, OUTD, PtXTb, OUTD, OUTD,
            (float*)alt, DIM, riv, GAMMA, ssacc, 0, 0);
        rsqrt_k<<<N_ROWS / 256, 256, 0, stream>>>(ssacc, riv);
        ushort* tmp = xm; xm = alt; alt = tmp;   // ping-pong
    }

    // final: out = relu(X@W1 + b1) @ W2 + b2  (unnormalized master, rv=nullptr)
    zgemm_k<<<N_ROWS / 64, 256, 0, stream>>>(xm, W1T, b1, z, nullptr);
    head_k<<<N_ROWS / 256, 256, 0, stream>>>(z, W2, b2, Pb, PTb, out, 0);
}

// Round 3
// 964.009 us; speedup vs baseline: 1.2446x; 1.1910x over previous
//
#include <hip/hip_runtime.h>

// CKAFormer R10 (from R9; R9 post-mortem: big path fixed the G gemm (out of
// top-5) but castgp_k became #1 at 53us x6: FETCH 98.5MB vs 23MB logical —
// the 16-way z-reduction was fused into the uncoalesced mirror-gather (lower-
// tri reads stride 256B, 2 useful bytes/64B line, x16 z). Fix: SPLIT PASSES.
// - reduce_k (new): coalesced u16x8 f32-sum of z-partials -> compact bf16
//   Gsum [36][128][128] (1.18MB) + PXsum [1024][64] (128KB), placed in the
//   dead PTb region (no new footprint). ~23MB coalesced ~ 4-5us.
// - castgp_k: pure gather/mirror/swizzle of the 1.3MB L2-resident sums, read
//   exactly once; negate = raw bf16 sign-bit XOR. Bit-identical output to R9.
// - Everything else R9-proven: dual ws_size path, zero-atomic split-K partial
//   gemms (G: R7's XCD-affine 8*36*2 grid), bf16 ping-pong master, pre-swizzled
//   layouts + global_load_lds 16B staging, fused rownorm, lb(256,3).

#define N_ROWS 16384
#define DIM 1024
#define HID 16
#define OUTD 64
#define DEPTH 6
#define GAMMA 1e-4f

typedef short bf16x8 __attribute__((ext_vector_type(8)));
typedef unsigned short u16x8 __attribute__((ext_vector_type(8)));
typedef float f32x4 __attribute__((ext_vector_type(4)));

#define AS1C(p) ((const __attribute__((address_space(1))) void*)(p))
#define AS3(p)  ((__attribute__((address_space(3))) void*)(p))

__device__ __forceinline__ unsigned short f2bf(float f) {
    unsigned u = __builtin_bit_cast(unsigned, f);
    u += 0x7fffu + ((u >> 16) & 1u);   // round-to-nearest-even
    return (unsigned short)(u >> 16);
}
__device__ __forceinline__ float b2f(ushort u) {
    unsigned x = ((unsigned)u) << 16;
    return __builtin_bit_cast(float, x);
}
// stored offset of logical element n within a swizzled row keyed by (row&7)
__device__ __forceinline__ int swz(int n, int row) {
    return (n & ~63) | ((((n >> 3) & 7) ^ (row & 7)) << 3) | (n & 7);
}

// ---------------------------------------------------------------------------
// Once per launch: master Xm = bf16(X) swizzled rows + rinv[row] = 1/||X[row]||.
__global__ __launch_bounds__(256) void tobf16_k(const float* __restrict__ X,
        ushort* __restrict__ Xm, float* __restrict__ rinv) {
    int row = blockIdx.x, t = threadIdx.x;
    float4 v = ((const float4*)(X + (size_t)row * DIM))[t];
    ushort4 o4;
    o4.x = f2bf(v.x); o4.y = f2bf(v.y); o4.z = f2bf(v.z); o4.w = f2bf(v.w);
    *(ushort4*)(Xm + (size_t)row * DIM + swz(t * 4, row)) = o4;
    float ss = v.x * v.x + v.y * v.y + v.z * v.z + v.w * v.w;
    for (int o = 32; o > 0; o >>= 1) ss += __shfl_down(ss, o);
    __shared__ float wsum[4];
    if ((t & 63) == 0) wsum[t >> 6] = ss;
    __syncthreads();
    if (t == 0) rinv[row] = 1.0f / sqrtf(wsum[0] + wsum[1] + wsum[2] + wsum[3]);
}

// ---------------------------------------------------------------------------
__global__ __launch_bounds__(256) void rsqrt_k(const float* __restrict__ ssacc,
        float* __restrict__ rinv) {
    int i = blockIdx.x * 256 + threadIdx.x;
    rinv[i] = 1.0f / sqrtf(ssacc[i]);
}

// ---------------------------------------------------------------------------
// XnT[d][k] = bf16(Xm[k][d] * rinv[k]), swizzled by d. LDS 64x65 f32 tile.
__global__ __launch_bounds__(256) void transpose_k(const ushort* __restrict__ Xm,
        const float* __restrict__ rinv, ushort* __restrict__ XnT) {
    int r0 = blockIdx.x * 64;   // source row (k) tile
    int c0 = blockIdx.y * 64;   // source col (d) tile
    int t = threadIdx.x;
    __shared__ float ts[64 * 65];
    __shared__ float riS[64];
    if (t < 64) riS[t] = rinv[r0 + t];
    __syncthreads();
#pragma unroll
    for (int i = 0; i < 2; ++i) {
        int idx = i * 256 + t;
        int r = idx >> 3, lg = idx & 7;
        int rr = r0 + r;
        const ushort* p = Xm + (size_t)rr * DIM + c0 + ((lg ^ (rr & 7)) << 3);
        u16x8 a = *(const u16x8*)p;
        float s = riS[r];
        float* d = &ts[r * 65 + lg * 8];
#pragma unroll
        for (int u = 0; u < 8; ++u) d[u] = b2f(a[u]) * s;
    }
    __syncthreads();
#pragma unroll
    for (int i = 0; i < 2; ++i) {
        int g = i * 256 + t;
        int c = g >> 3;
        int rg = g & 7;
        u16x8 pk;
#pragma unroll
        for (int u = 0; u < 8; ++u) pk[u] = f2bf(ts[(rg * 8 + u) * 65 + c]);
        *(u16x8*)(XnT + (size_t)(c0 + c) * N_ROWS + r0 + ((rg ^ (c & 7)) << 3)) = pk;
    }
}

// ---------------------------------------------------------------------------
__global__ __launch_bounds__(256) void prep_w1t_k(const float* __restrict__ W1,
        ushort* __restrict__ W1T) {
    int idx = blockIdx.x * 256 + threadIdx.x;   // 16384
    int h = idx >> 10, j = idx & 1023;
    W1T[idx] = f2bf(W1[j * HID + h]);
}

// ---------------------------------------------------------------------------
// z[m][h] = rv[m] * (Xm[m]·W1[:,h]) + b1[h]   (rv=nullptr -> no scale; final).
__global__ __launch_bounds__(256) void zgemm_k(const ushort* __restrict__ Xm,
        const ushort* __restrict__ W1T, const float* __restrict__ b1,
        float* __restrict__ z, const float* __restrict__ rv) {
    int t = threadIdx.x;
    int wave = t >> 6, lane = t & 63;
    int rl = lane & 15, q = lane >> 4;
    int rowbase = blockIdx.x * 64 + wave * 16;
    int m = rowbase + rl;
    int msw = m & 7;
    const ushort* arow = Xm + (size_t)m * DIM;
    const ushort* brow = W1T + (size_t)rl * DIM + q * 8;
    f32x4 acc = {0.f, 0.f, 0.f, 0.f};
#pragma unroll 8
    for (int kt = 0; kt < DIM; kt += 32) {
        int gl = ((kt >> 3) & 7) | q;
        int off = (kt & ~63) + ((gl ^ msw) << 3);
        bf16x8 a = *(const bf16x8*)(arow + off);
        bf16x8 b = *(const bf16x8*)(brow + kt);
        acc = __builtin_amdgcn_mfma_f32_16x16x32_bf16(a, b, acc, 0, 0, 0);
    }
#pragma unroll
    for (int rg = 0; rg < 4; ++rg) {
        int mm = rowbase + q * 4 + rg;
        float s = rv ? rv[mm] : 1.0f;
        z[(size_t)mm * HID + rl] = acc[rg] * s + b1[rl];
    }
}

// ---------------------------------------------------------------------------
// Per row: h = relu(z); logits = h@W2 + b2; softmax -> Pb (swizzled by m&7)
// + PTb (rows o, swizzled by o&7), or (do_softmax=0) logits f32 to out.
__global__ __launch_bounds__(256) void head_k(const float* __restrict__ z,
        const float* __restrict__ W2, const float* __restrict__ b2,
        ushort* __restrict__ Pb, ushort* __restrict__ PTb,
        float* __restrict__ out, int do_softmax) {
    __shared__ float w2s[HID * OUTD];
    __shared__ float b2s[OUTD];
    int t = threadIdx.x;
    ((float4*)w2s)[t] = ((const float4*)W2)[t];
    if (t < OUTD) b2s[t] = b2[t];
    __syncthreads();
    int m = blockIdx.x * 256 + t;
    float h[HID];
    const float4* zp = (const float4*)(z + (size_t)m * HID);
#pragma unroll
    for (int i = 0; i < 4; ++i) {
        float4 v = zp[i];
        h[i * 4 + 0] = fmaxf(v.x, 0.f); h[i * 4 + 1] = fmaxf(v.y, 0.f);
        h[i * 4 + 2] = fmaxf(v.z, 0.f); h[i * 4 + 3] = fmaxf(v.w, 0.f);
    }
    float lo[OUTD];
#pragma unroll
    for (int o = 0; o < OUTD; ++o) lo[o] = b2s[o];
    for (int i = 0; i < HID; ++i) {
        float hv = h[i];
#pragma unroll
        for (int o = 0; o < OUTD; ++o) lo[o] += hv * w2s[i * OUTD + o];
    }
    if (do_softmax) {
        float mx = lo[0];
#pragma unroll
        for (int o = 1; o < OUTD; ++o) mx = fmaxf(mx, lo[o]);
        float sm = 0.f;
#pragma unroll
        for (int o = 0; o < OUTD; ++o) { float e = __expf(lo[o] - mx); lo[o] = e; sm += e; }
        float inv = 1.0f / sm;
#pragma unroll
        for (int o8 = 0; o8 < 8; ++o8) {
            u16x8 pk;
#pragma unroll
            for (int u = 0; u < 8; ++u) pk[u] = f2bf(lo[o8 * 8 + u] * inv);
            ((u16x8*)(Pb + (size_t)m * OUTD))[o8 ^ (m & 7)] = pk;
        }
#pragma unroll
        for (int o = 0; o < OUTD; ++o)
            PTb[(size_t)o * N_ROWS + swz(m, o)] = f2bf(lo[o] * inv);
    } else {
        float4* op = (float4*)(out + (size_t)m * OUTD);
#pragma unroll
        for (int o4 = 0; o4 < 16; ++o4) {
            float4 v; v.x = lo[o4 * 4 + 0]; v.y = lo[o4 * 4 + 1];
            v.z = lo[o4 * 4 + 2]; v.w = lo[o4 * 4 + 3];
            op[o4] = v;
        }
    }
}

// ---------------------------------------------------------------------------
// Pass A: coalesced split-K reduction. Gp: [nzg][36*16384] bf16 -> Gsum (f32
// sum, one bf16 round); PXp: [nzp][65536] bf16 -> PXsum. u16x8 lanes.
__global__ __launch_bounds__(256) void reduce_k(const ushort* __restrict__ Gp,
        const ushort* __restrict__ PXp, ushort* __restrict__ Gsum,
        ushort* __restrict__ PXsum, int nzg, int nzp) {
    int idx = blockIdx.x * 256 + threadIdx.x;   // 81920 units of 8 elems
    if (idx < 73728) {
        size_t off = (size_t)idx * 8;
        float acc[8] = {0.f, 0.f, 0.f, 0.f, 0.f, 0.f, 0.f, 0.f};
        for (int zz = 0; zz < nzg; ++zz) {
            u16x8 v = *(const u16x8*)(Gp + (size_t)zz * 589824 + off);
#pragma unroll
            for (int u = 0; u < 8; ++u) acc[u] += b2f(v[u]);
        }
        u16x8 o;
#pragma unroll
        for (int u = 0; u < 8; ++u) o[u] = f2bf(acc[u]);
        *(u16x8*)(Gsum + off) = o;
    } else {
        size_t off = (size_t)(idx - 73728) * 8;
        float acc[8] = {0.f, 0.f, 0.f, 0.f, 0.f, 0.f, 0.f, 0.f};
        for (int zz = 0; zz < nzp; ++zz) {
            u16x8 v = *(const u16x8*)(PXp + (size_t)zz * 65536 + off);
#pragma unroll
            for (int u = 0; u < 8; ++u) acc[u] += b2f(v[u]);
        }
        u16x8 o;
#pragma unroll
        for (int u = 0; u < 8; ++u) o[u] = f2bf(acc[u]);
        *(u16x8*)(PXsum + off) = o;
    }
}

// ---------------------------------------------------------------------------
// Pass B: pure gather/permute of the summed compact buffers (L2-resident).
// Gb[n][swz] = Gsum mirrored upper-tri, negated via sign-bit XOR;
// PtXTb[d][swz] = PXsum copy.
__global__ __launch_bounds__(256) void castgp_k(const ushort* __restrict__ Gsum,
        const ushort* __restrict__ PXsum, ushort* __restrict__ Gb,
        ushort* __restrict__ PtXTb) {
    int idx = blockIdx.x * 256 + threadIdx.x;   // 278528 units
    if (idx < 262144) {
        int n = idx >> 8;
        int so = (idx & 255) * 4;
        int k0 = (so & ~63) | ((((so >> 3) & 7) ^ (n & 7)) << 3) | (so & 7);
        ushort po[4];
#pragma unroll
        for (int u = 0; u < 4; ++u) {
            int kk = k0 + u;
            int a = min(n, kk), b = max(n, kk);
            int tm = a >> 7, tn = b >> 7;
            int tlin = tm * 8 - ((tm * (tm - 1)) >> 1) + (tn - tm);
            size_t off = (size_t)tlin * 16384 + (size_t)(a & 127) * 128 + (b & 127);
            po[u] = (ushort)(Gsum[off] ^ 0x8000u);   // negate via sign bit
        }
        ushort4 o; o.x = po[0]; o.y = po[1]; o.z = po[2]; o.w = po[3];
        *(ushort4*)(Gb + (size_t)n * DIM + so) = o;
    } else {
        int vv = idx - 262144;                  // 16384 units
        int d = vv >> 4;
        int so = (vv & 15) * 4;
        int k0 = ((((so >> 3) & 7) ^ (d & 7)) << 3) | (so & 7);
        const ushort* src = PXsum + (size_t)d * OUTD + k0;
        ushort4 o; o.x = src[0]; o.y = src[1]; o.z = src[2]; o.w = src[3];
        *(ushort4*)(PtXTb + (size_t)d * OUTD + so) = o;
    }
}

// ---------------------------------------------------------------------------
// NT MFMA GEMM (R5-proven body). Non-TRI: m0 = blockIdx.x*BM, n0 = blockIdx.y*BN,
// zidx = blockIdx.z. TRI: flattened grid; nz==16 -> R7 mapping (grid 8*36*2,
// zidx = (bid&7)|(zhi<<3), z-low on XCD for L2 k-chunk affinity); nz==4 ->
// grid 36*4, zidx = bid&3. Upper-triangle 128x128 tiles.
// EPI 0: plain bf16 pair-stores into per-z partial buffer (zidx*pstride elems);
//        TRI uses compact tile addressing, non-TRI uses m*ldc+n.
// EPI 1: seg0 acc scaled by rinv[m]; epilogue writes bf16 master + row
//        sum-of-squares into ssacc.
template<int BM, int BN, int EPI, int TRI>
__global__ __launch_bounds__(256, 3) void gemm_nt_k(
        const ushort* __restrict__ A0, int lda0,
        const ushort* __restrict__ B0, int ldb0, int k0len,
        const ushort* __restrict__ A1, int lda1,
        const ushort* __restrict__ B1, int ldb1, int k1len,
        float* __restrict__ C, int ldc,
        const float* __restrict__ rinv, float gamma,
        float* __restrict__ ssacc, int pstride, int nz) {
    constexpr int WTN = BN / 2;
    constexpr int NF = WTN / 16;
    constexpr int NAW = BM / 64;     // waves staging A
    constexpr int NBW = BN / 64;     // waves staging B
    __shared__ ushort ls[(BM + BN) * 64];
    ushort* lsA = ls;
    ushort* lsB = ls + BM * 64;
    int t = threadIdx.x;
    int wave = t >> 6, lane = t & 63;
    int rl = lane & 15, q = lane >> 4;
    int wm = wave & 1, wn = wave >> 1;
    int m0, n0, zidx, tlin = 0;
    if (TRI) {
        int bid = blockIdx.x;
        int bx, tm = 0;
        if (nz == 16) {                 // R7-proven mapping: grid 8*36*2
            int rest = bid >> 3;
            bx = rest % 36;
            int zhi = rest / 36;
            zidx = (bid & 7) | (zhi << 3);
        } else {                        // fallback: grid 36*4
            zidx = bid & 3;
            bx = bid >> 2;
        }
        tlin = bx;
        while (bx >= 8 - tm) { bx -= 8 - tm; ++tm; }
        m0 = tm * 128; n0 = (tm + bx) * 128;
    } else {
        m0 = blockIdx.x * BM; n0 = blockIdx.y * BN; zidx = blockIdx.z;
    }
    int lrow8 = lane >> 3, lgrp = lane & 7;
    bool isA = wave < NAW;
    bool active = wave < NAW + NBW;
    int wlocal = isA ? wave : wave - NAW;
    ushort* dstb = ls + (isA ? 0 : BM * 64) + wlocal * 4096;

    f32x4 acc[4][NF];
#pragma unroll
    for (int i = 0; i < 4; ++i)
#pragma unroll
        for (int j = 0; j < NF; ++j) acc[i][j] = f32x4{0.f, 0.f, 0.f, 0.f};
    float rvv[4][4];

    for (int seg = 0; seg < 2; ++seg) {
        int klen = seg ? k1len : k0len;
        if (klen > 0) {
            const ushort* OPA = seg ? A1 : A0;
            const ushort* OPB = seg ? B1 : B0;
            int ldaS = seg ? lda1 : lda0;
            int ldbS = seg ? ldb1 : ldb0;
            int kb = seg ? 0 : zidx * k0len;
            const ushort* srcb;
            size_t ldS;
            if (isA) {
                srcb = OPA + (size_t)(m0 + wlocal * 64 + lrow8) * ldaS + lgrp * 8;
                ldS = (size_t)ldaS;
            } else {
                srcb = OPB + (size_t)(n0 + wlocal * 64 + lrow8) * ldbS + lgrp * 8;
                ldS = (size_t)ldbS;
            }
            srcb += kb;
            for (int kt = 0; kt < klen; kt += 64) {
                if (active) {
#pragma unroll
                    for (int c = 0; c < 8; ++c)
                        __builtin_amdgcn_global_load_lds(AS1C(srcb + c * 8 * ldS),
                                                         AS3(dstb + c * 512), 16, 0, 0);
                    srcb += 64;
                }
                __syncthreads();
#pragma unroll
                for (int s = 0; s < 2; ++s) {
                    bf16x8 af[4], bfr[NF];
#pragma unroll
                    for (int i = 0; i < 4; ++i) {
                        int row = wm * 64 + i * 16 + rl;
                        int sg = ((s << 2) | q) ^ (row & 7);
                        af[i] = *(const bf16x8*)&lsA[row * 64 + sg * 8];
                    }
#pragma unroll
                    for (int j = 0; j < NF; ++j) {
                        int row = wn * WTN + j * 16 + rl;
                        int sg = ((s << 2) | q) ^ (row & 7);
                        bfr[j] = *(const bf16x8*)&lsB[row * 64 + sg * 8];
                    }
#pragma unroll
                    for (int i = 0; i < 4; ++i)
#pragma unroll
                        for (int j = 0; j < NF; ++j)
                            acc[i][j] = __builtin_amdgcn_mfma_f32_16x16x32_bf16(
                                af[i], bfr[j], acc[i][j], 0, 0, 0);
                }
                __syncthreads();
            }
        }
        if (EPI == 1 && seg == 0) {
#pragma unroll
            for (int i = 0; i < 4; ++i)
#pragma unroll
                for (int rg = 0; rg < 4; ++rg)
                    rvv[i][rg] = rinv[m0 + wm * 64 + i * 16 + q * 4 + rg];
#pragma unroll
            for (int i = 0; i < 4; ++i)
#pragma unroll
                for (int j = 0; j < NF; ++j)
#pragma unroll
                    for (int rg = 0; rg < 4; ++rg)
                        acc[i][j][rg] *= rvv[i][rg];
        }
    }

    if (EPI == 0) {
        // plain bf16 pair stores into this z-slice's partial buffer
        ushort* Cb = (ushort*)C + (size_t)zidx * (size_t)pstride;
#pragma unroll
        for (int i = 0; i < 4; ++i)
#pragma unroll
            for (int j = 0; j < NF; ++j)
#pragma unroll
                for (int rg = 0; rg < 4; ++rg) {
                    float v = acc[i][j][rg];
                    float vp = __shfl_xor(v, 1);   // partner lane's (n^1) value
                    if ((rl & 1) == 0) {
                        int ml = wm * 64 + i * 16 + q * 4 + rg;
                        int nl = wn * WTN + j * 16 + rl;
                        size_t off;
                        if (TRI)
                            off = (size_t)tlin * (BM * BN) + (size_t)ml * BN + nl;
                        else
                            off = (size_t)(m0 + ml) * ldc + (n0 + nl);
                        unsigned pk = (unsigned)f2bf(v) | ((unsigned)f2bf(vp) << 16);
                        *(unsigned*)(Cb + off) = pk;
                    }
                }
    } else {
#pragma unroll
        for (int i = 0; i < 4; ++i)
#pragma unroll
            for (int rg = 0; rg < 4; ++rg) {
                int m = m0 + wm * 64 + i * 16 + q * 4 + rg;
                float ssl = 0.f;
#pragma unroll
                for (int j = 0; j < NF; ++j) {
                    int n = n0 + wn * WTN + j * 16 + rl;
                    int so = swz(n, m);
                    float base = b2f(A0[(size_t)m * lda0 + so]);
                    float vf = base * rvv[i][rg] + gamma * acc[i][j][rg];
                    ((ushort*)C)[(size_t)m * ldc + so] = f2bf(vf);
                    ssl += vf * vf;
                }
                ssl += __shfl_xor(ssl, 1);
                ssl += __shfl_xor(ssl, 2);
                ssl += __shfl_xor(ssl, 4);
                ssl += __shfl_xor(ssl, 8);
                if (rl == 0) atomicAdd(&ssacc[m], ssl);
            }
    }
}

// ---------------------------------------------------------------------------
extern "C" void kernel_launch(void* const* d_in, const int* in_sizes, int n_in,
                              void* d_out, int out_size, void* d_ws, size_t ws_size,
                              hipStream_t stream) {
    const float* X = (const float*)d_in[0];
    const float* W1 = (const float*)d_in[1];
    const float* b1 = (const float*)d_in[2];
    const float* W2 = (const float*)d_in[3];
    const float* b2 = (const float*)d_in[4];
    float* out = (float*)d_out;
    char* ws = (char*)d_ws;

    constexpr size_t O_BufA    = 0;                                     // 33,554,432
    constexpr size_t O_BufB    = O_BufA + (size_t)N_ROWS * DIM * 2;     // 33,554,432
    constexpr size_t O_Pb      = O_BufB + (size_t)N_ROWS * DIM * 2;     //  2,097,152
    constexpr size_t O_PTb     = O_Pb + (size_t)N_ROWS * OUTD * 2;      //  2,097,152
    constexpr size_t O_Gb      = O_PTb + (size_t)OUTD * N_ROWS * 2;     //  2,097,152
    constexpr size_t O_PtXTb   = O_Gb + (size_t)DIM * DIM * 2;          //    131,072
    constexpr size_t O_riv     = O_PtXTb + (size_t)DIM * OUTD * 2;      //     65,536
    constexpr size_t O_W1T     = O_riv + (size_t)N_ROWS * 4;            //     32,768
    constexpr size_t O_ssacc   = O_W1T + (size_t)HID * DIM * 2;         //     65,536
    constexpr size_t O_scratch = O_ssacc + (size_t)N_ROWS * 4;          // = 73,695,232
    // scratch time-shares: z (1,048,576 f32, live zgemm->head) and Gpart
    // (big: 16 x 589824 x 2 = 18,874,368 -> ws end 92,569,600;
    //  small: 4 x 589824 x 2 = 4,718,592 -> ws end 78,413,824).
    // PXpart lives in d_out (4MB, dead until final head_k):
    //  big: 32 z (exact fit); small: 8 z.
    // Gsum (1,179,648) + PXsum (131,072) live in the PTb region (dead between
    // the PtX gemm and next head_k; 1,310,720 <= 2,097,152).
    constexpr size_t WS_BIG = O_scratch + (size_t)16 * 589824 * 2;

    ushort* bufA  = (ushort*)(ws + O_BufA);
    ushort* bufB  = (ushort*)(ws + O_BufB);
    ushort* Pb    = (ushort*)(ws + O_Pb);
    ushort* PTb   = (ushort*)(ws + O_PTb);
    ushort* Gb    = (ushort*)(ws + O_Gb);
    ushort* PtXTb = (ushort*)(ws + O_PtXTb);
    float*  riv   = (float*)(ws + O_riv);
    ushort* W1T   = (ushort*)(ws + O_W1T);
    float*  ssacc = (float*)(ws + O_ssacc);
    float*  z     = (float*)(ws + O_scratch);
    ushort* Gpart = (ushort*)(ws + O_scratch);
    ushort* PXpart = (ushort*)d_out;
    ushort* Gsum  = PTb;                       // PTb region reuse (dead)
    ushort* PXsum = PTb + 589824;
    (void)in_sizes; (void)n_in; (void)out_size;

    const bool big = ws_size >= WS_BIG;
    const int nzg = big ? 16 : 4;
    const int nzp = big ? 32 : 8;

    prep_w1t_k<<<64, 256, 0, stream>>>(W1, W1T);
    tobf16_k<<<N_ROWS, 256, 0, stream>>>(X, bufA, riv);

    ushort* xm  = bufA;   // current master X_t (bf16, swizzled rows)
    ushort* alt = bufB;   // scratch: XnT during iter, then becomes X_{t+1}

    for (int it = 0; it < DEPTH; ++it) {
        transpose_k<<<dim3(N_ROWS / 64, DIM / 64), 256, 0, stream>>>(xm, riv, alt);
        zgemm_k<<<N_ROWS / 64, 256, 0, stream>>>(xm, W1T, b1, z, riv);
        head_k<<<N_ROWS / 256, 256, 0, stream>>>(z, W2, b2, Pb, PTb, nullptr, 1);
        if (big) {
            // G = XnT . XnT^T : 36 upper-tri tiles x split-K 16 on R7's
            // XCD-affine flattened grid; plain partials (clobbers dead z)
            gemm_nt_k<128, 128, 0, 1><<<dim3(8 * 36 * 2, 1, 1), 256, 0, stream>>>(
                alt, N_ROWS, alt, N_ROWS, 1024,
                nullptr, 0, nullptr, 0, 0,
                (float*)Gpart, 128, nullptr, 0.f, nullptr, 36 * 16384, 16);
            // PtX^T[d][o] = XnT . PTb^T : split-K 32, partials fill d_out
            gemm_nt_k<128, 64, 0, 0><<<dim3(8, 1, 32), 256, 0, stream>>>(
                alt, N_ROWS, PTb, N_ROWS, 512,
                nullptr, 0, nullptr, 0, 0,
                (float*)PXpart, OUTD, nullptr, 0.f, nullptr, DIM * OUTD, 0);
        } else {
            gemm_nt_k<128, 128, 0, 1><<<dim3(36 * 4, 1, 1), 256, 0, stream>>>(
                alt, N_ROWS, alt, N_ROWS, 4096,
                nullptr, 0, nullptr, 0, 0,
                (float*)Gpart, 128, nullptr, 0.f, nullptr, 36 * 16384, 4);
            gemm_nt_k<128, 64, 0, 0><<<dim3(8, 1, 8), 256, 0, stream>>>(
                alt, N_ROWS, PTb, N_ROWS, 2048,
                nullptr, 0, nullptr, 0, 0,
                (float*)PXpart, OUTD, nullptr, 0.f, nullptr, DIM * OUTD, 0);
        }
        // Pass A: coalesced z-reduction into compact sums (PTb now dead)
        reduce_k<<<320, 256, 0, stream>>>(Gpart, PXpart, Gsum, PXsum, nzg, nzp);
        // Pass B: gather/mirror/swizzle of the L2-resident sums
        castgp_k<<<1088, 256, 0, stream>>>(Gsum, PXsum, Gb, PtXTb);
        hipMemsetAsync(ws + O_ssacc, 0, (size_t)N_ROWS * 4, stream);
        // X_{t+1} = Xn + g*(P@PtX - Xn@G); writes `alt`; accumulates ssacc
        gemm_nt_k<128, 128, 1, 0><<<dim3(N_ROWS / 128, DIM / 128, 1), 256, 0, stream>>>(
            xm, DIM, Gb, DIM, 1024,
            Pb, OUTD, PtXTb, OUTD, OUTD,
            (float*)alt, DIM, riv, GAMMA, ssacc, 0, 0);
        rsqrt_k<<<N_ROWS / 256, 256, 0, stream>>>(ssacc, riv);
        ushort* tmp = xm; xm = alt; alt = tmp;   // ping-pong
    }

    // final: out = relu(X@W1 + b1) @ W2 + b2  (unnormalized master, rv=nullptr)
    zgemm_k<<<N_ROWS / 64, 256, 0, stream>>>(xm, W1T, b1, z, nullptr);
    head_k<<<N_ROWS / 256, 256, 0, stream>>>(z, W2, b2, Pb, PTb, out, 0);
}

// Round 4
// 908.729 us; speedup vs baseline: 1.3203x; 1.0608x over previous
//
#include <hip/hip_runtime.h>

// CKAFormer R11 (from R10; R10 post-mortem: EPI1 gemm (6x51.5us, 709 TF,
// MfmaUtil 28.6%) is AT the 128^2 2-barrier structure's ceiling after
// short-K/epilogue adjustment (m97 ref 37%); same for G. 8-phase rewrite is
// the only gemm lever and can't be race-screened one-shot. What's NOT at
// ceiling: serial glue — 10 dispatches/iter, several at 1 block/CU.
// R11 = GRID-FUSION of independent subgraphs + dispatch elimination:
// - txz_k: transpose(4096 blks) U zgemm(256 blks, was 1/CU latency-bound) in
//   one grid — both read xm+ss only, write disjoint XnT/z.
// - gp_k: G-gemm(576) U PtX-gemm(256, was 1/CU) in one grid — both read XnT,
//   write disjoint partial buffers.
// - rsqrt_k + riv buffer ELIMINATED: consumers compute 1/sqrtf(ssacc[m])
//   inline (bit-identical IEEE => absmax unchanged). ssacc ping-pongs
//   (ssB reuses old riv slot); castgp_k zeroes the next ssacc (memset gone).
// - 10 -> 6 dispatches/iter. Gemm bodies byte-identical to R10 (shared
//   __device__ template), layouts/WS identical to R10.

#define N_ROWS 16384
#define DIM 1024
#define HID 16
#define OUTD 64
#define DEPTH 6
#define GAMMA 1e-4f

typedef short bf16x8 __attribute__((ext_vector_type(8)));
typedef unsigned short u16x8 __attribute__((ext_vector_type(8)));
typedef float f32x4 __attribute__((ext_vector_type(4)));

#define AS1C(p) ((const __attribute__((address_space(1))) void*)(p))
#define AS3(p)  ((__attribute__((address_space(3))) void*)(p))

__device__ __forceinline__ unsigned short f2bf(float f) {
    unsigned u = __builtin_bit_cast(unsigned, f);
    u += 0x7fffu + ((u >> 16) & 1u);   // round-to-nearest-even
    return (unsigned short)(u >> 16);
}
__device__ __forceinline__ float b2f(ushort u) {
    unsigned x = ((unsigned)u) << 16;
    return __builtin_bit_cast(float, x);
}
// stored offset of logical element n within a swizzled row keyed by (row&7)
__device__ __forceinline__ int swz(int n, int row) {
    return (n & ~63) | ((((n >> 3) & 7) ^ (row & 7)) << 3) | (n & 7);
}

// ---------------------------------------------------------------------------
// Once per launch: master Xm = bf16(X) swizzled rows + ssout[row] = ||X[row]||^2.
__global__ __launch_bounds__(256) void tobf16_k(const float* __restrict__ X,
        ushort* __restrict__ Xm, float* __restrict__ ssout) {
    int row = blockIdx.x, t = threadIdx.x;
    float4 v = ((const float4*)(X + (size_t)row * DIM))[t];
    ushort4 o4;
    o4.x = f2bf(v.x); o4.y = f2bf(v.y); o4.z = f2bf(v.z); o4.w = f2bf(v.w);
    *(ushort4*)(Xm + (size_t)row * DIM + swz(t * 4, row)) = o4;
    float ss = v.x * v.x + v.y * v.y + v.z * v.z + v.w * v.w;
    for (int o = 32; o > 0; o >>= 1) ss += __shfl_down(ss, o);
    __shared__ float wsum[4];
    if ((t & 63) == 0) wsum[t >> 6] = ss;
    __syncthreads();
    if (t == 0) ssout[row] = wsum[0] + wsum[1] + wsum[2] + wsum[3];
}

// ---------------------------------------------------------------------------
// XnT[d][k] = bf16(Xm[k][d] / ||X[k]||), swizzled by d. LDS 64x65 f32 tile.
__device__ __forceinline__ void transpose_body(const ushort* __restrict__ Xm,
        const float* __restrict__ ss, ushort* __restrict__ XnT,
        int bx, int by, float* ts, float* riS) {
    int r0 = bx * 64;   // source row (k) tile
    int c0 = by * 64;   // source col (d) tile
    int t = threadIdx.x;
    if (t < 64) riS[t] = 1.0f / sqrtf(ss[r0 + t]);
    __syncthreads();
#pragma unroll
    for (int i = 0; i < 2; ++i) {
        int idx = i * 256 + t;
        int r = idx >> 3, lg = idx & 7;
        int rr = r0 + r;
        const ushort* p = Xm + (size_t)rr * DIM + c0 + ((lg ^ (rr & 7)) << 3);
        u16x8 a = *(const u16x8*)p;
        float s = riS[r];
        float* d = &ts[r * 65 + lg * 8];
#pragma unroll
        for (int u = 0; u < 8; ++u) d[u] = b2f(a[u]) * s;
    }
    __syncthreads();
#pragma unroll
    for (int i = 0; i < 2; ++i) {
        int g = i * 256 + t;
        int c = g >> 3;
        int rg = g & 7;
        u16x8 pk;
#pragma unroll
        for (int u = 0; u < 8; ++u) pk[u] = f2bf(ts[(rg * 8 + u) * 65 + c]);
        *(u16x8*)(XnT + (size_t)(c0 + c) * N_ROWS + r0 + ((rg ^ (c & 7)) << 3)) = pk;
    }
}

// ---------------------------------------------------------------------------
// z[m][h] = (Xm[m]·W1[:,h]) / ||X[m]|| + b1[h]   (ss=nullptr -> no scale; final).
__device__ __forceinline__ void zgemm_body(const ushort* __restrict__ Xm,
        const ushort* __restrict__ W1T, const float* __restrict__ b1,
        float* __restrict__ z, const float* __restrict__ ss, int bidx) {
    int t = threadIdx.x;
    int wave = t >> 6, lane = t & 63;
    int rl = lane & 15, q = lane >> 4;
    int rowbase = bidx * 64 + wave * 16;
    int m = rowbase + rl;
    int msw = m & 7;
    const ushort* arow = Xm + (size_t)m * DIM;
    const ushort* brow = W1T + (size_t)rl * DIM + q * 8;
    f32x4 acc = {0.f, 0.f, 0.f, 0.f};
#pragma unroll 8
    for (int kt = 0; kt < DIM; kt += 32) {
        int gl = ((kt >> 3) & 7) | q;
        int off = (kt & ~63) + ((gl ^ msw) << 3);
        bf16x8 a = *(const bf16x8*)(arow + off);
        bf16x8 b = *(const bf16x8*)(brow + kt);
        acc = __builtin_amdgcn_mfma_f32_16x16x32_bf16(a, b, acc, 0, 0, 0);
    }
#pragma unroll
    for (int rg = 0; rg < 4; ++rg) {
        int mm = rowbase + q * 4 + rg;
        float s = ss ? 1.0f / sqrtf(ss[mm]) : 1.0f;
        z[(size_t)mm * HID + rl] = acc[rg] * s + b1[rl];
    }
}

// ---------------------------------------------------------------------------
// Fused transpose (blocks 0..4095) + zgemm (blocks 4096..4351). Independent:
// both only read xm+ss; disjoint writes (XnT vs z).
__global__ __launch_bounds__(256) void txz_k(const ushort* __restrict__ Xm,
        const float* __restrict__ ss, ushort* __restrict__ XnT,
        const ushort* __restrict__ W1T, const float* __restrict__ b1,
        float* __restrict__ z) {
    __shared__ float ts[64 * 65];
    __shared__ float riS[64];
    int bid = blockIdx.x;
    if (bid < 4096) transpose_body(Xm, ss, XnT, bid & 255, bid >> 8, ts, riS);
    else            zgemm_body(Xm, W1T, b1, z, ss, bid - 4096);
}

// standalone wrappers (small path / final)
__global__ __launch_bounds__(256) void transpose_k(const ushort* __restrict__ Xm,
        const float* __restrict__ ss, ushort* __restrict__ XnT) {
    __shared__ float ts[64 * 65];
    __shared__ float riS[64];
    transpose_body(Xm, ss, XnT, blockIdx.x, blockIdx.y, ts, riS);
}
__global__ __launch_bounds__(256) void zgemm_k(const ushort* __restrict__ Xm,
        const ushort* __restrict__ W1T, const float* __restrict__ b1,
        float* __restrict__ z, const float* __restrict__ ss) {
    zgemm_body(Xm, W1T, b1, z, ss, blockIdx.x);
}

// ---------------------------------------------------------------------------
__global__ __launch_bounds__(256) void prep_w1t_k(const float* __restrict__ W1,
        ushort* __restrict__ W1T) {
    int idx = blockIdx.x * 256 + threadIdx.x;   // 16384
    int h = idx >> 10, j = idx & 1023;
    W1T[idx] = f2bf(W1[j * HID + h]);
}

// ---------------------------------------------------------------------------
// Per row: h = relu(z); logits = h@W2 + b2; softmax -> Pb (swizzled by m&7)
// + PTb (rows o, swizzled by o&7), or (do_softmax=0) logits f32 to out.
__global__ __launch_bounds__(256) void head_k(const float* __restrict__ z,
        const float* __restrict__ W2, const float* __restrict__ b2,
        ushort* __restrict__ Pb, ushort* __restrict__ PTb,
        float* __restrict__ out, int do_softmax) {
    __shared__ float w2s[HID * OUTD];
    __shared__ float b2s[OUTD];
    int t = threadIdx.x;
    ((float4*)w2s)[t] = ((const float4*)W2)[t];
    if (t < OUTD) b2s[t] = b2[t];
    __syncthreads();
    int m = blockIdx.x * 256 + t;
    float h[HID];
    const float4* zp = (const float4*)(z + (size_t)m * HID);
#pragma unroll
    for (int i = 0; i < 4; ++i) {
        float4 v = zp[i];
        h[i * 4 + 0] = fmaxf(v.x, 0.f); h[i * 4 + 1] = fmaxf(v.y, 0.f);
        h[i * 4 + 2] = fmaxf(v.z, 0.f); h[i * 4 + 3] = fmaxf(v.w, 0.f);
    }
    float lo[OUTD];
#pragma unroll
    for (int o = 0; o < OUTD; ++o) lo[o] = b2s[o];
    for (int i = 0; i < HID; ++i) {
        float hv = h[i];
#pragma unroll
        for (int o = 0; o < OUTD; ++o) lo[o] += hv * w2s[i * OUTD + o];
    }
    if (do_softmax) {
        float mx = lo[0];
#pragma unroll
        for (int o = 1; o < OUTD; ++o) mx = fmaxf(mx, lo[o]);
        float sm = 0.f;
#pragma unroll
        for (int o = 0; o < OUTD; ++o) { float e = __expf(lo[o] - mx); lo[o] = e; sm += e; }
        float inv = 1.0f / sm;
#pragma unroll
        for (int o8 = 0; o8 < 8; ++o8) {
            u16x8 pk;
#pragma unroll
            for (int u = 0; u < 8; ++u) pk[u] = f2bf(lo[o8 * 8 + u] * inv);
            ((u16x8*)(Pb + (size_t)m * OUTD))[o8 ^ (m & 7)] = pk;
        }
#pragma unroll
        for (int o = 0; o < OUTD; ++o)
            PTb[(size_t)o * N_ROWS + swz(m, o)] = f2bf(lo[o] * inv);
    } else {
        float4* op = (float4*)(out + (size_t)m * OUTD);
#pragma unroll
        for (int o4 = 0; o4 < 16; ++o4) {
            float4 v; v.x = lo[o4 * 4 + 0]; v.y = lo[o4 * 4 + 1];
            v.z = lo[o4 * 4 + 2]; v.w = lo[o4 * 4 + 3];
            op[o4] = v;
        }
    }
}

// ---------------------------------------------------------------------------
// Pass A: coalesced split-K reduction. Gp: [nzg][36*16384] bf16 -> Gsum (f32
// sum, one bf16 round); PXp: [nzp][65536] bf16 -> PXsum. u16x8 lanes.
__global__ __launch_bounds__(256) void reduce_k(const ushort* __restrict__ Gp,
        const ushort* __restrict__ PXp, ushort* __restrict__ Gsum,
        ushort* __restrict__ PXsum, int nzg, int nzp) {
    int idx = blockIdx.x * 256 + threadIdx.x;   // 81920 units of 8 elems
    if (idx < 73728) {
        size_t off = (size_t)idx * 8;
        float acc[8] = {0.f, 0.f, 0.f, 0.f, 0.f, 0.f, 0.f, 0.f};
        for (int zz = 0; zz < nzg; ++zz) {
            u16x8 v = *(const u16x8*)(Gp + (size_t)zz * 589824 + off);
#pragma unroll
            for (int u = 0; u < 8; ++u) acc[u] += b2f(v[u]);
        }
        u16x8 o;
#pragma unroll
        for (int u = 0; u < 8; ++u) o[u] = f2bf(acc[u]);
        *(u16x8*)(Gsum + off) = o;
    } else {
        size_t off = (size_t)(idx - 73728) * 8;
        float acc[8] = {0.f, 0.f, 0.f, 0.f, 0.f, 0.f, 0.f, 0.f};
        for (int zz = 0; zz < nzp; ++zz) {
            u16x8 v = *(const u16x8*)(PXp + (size_t)zz * 65536 + off);
#pragma unroll
            for (int u = 0; u < 8; ++u) acc[u] += b2f(v[u]);
        }
        u16x8 o;
#pragma unroll
        for (int u = 0; u < 8; ++u) o[u] = f2bf(acc[u]);
        *(u16x8*)(PXsum + off) = o;
    }
}

// ---------------------------------------------------------------------------
// Pass B: pure gather/permute of the summed compact buffers (L2-resident).
// Gb[n][swz] = Gsum mirrored upper-tri, negated via sign-bit XOR;
// PtXTb[d][swz] = PXsum copy. Also zeroes the next-iteration ssacc (64 KB).
__global__ __launch_bounds__(256) void castgp_k(const ushort* __restrict__ Gsum,
        const ushort* __restrict__ PXsum, ushort* __restrict__ Gb,
        ushort* __restrict__ PtXTb, float* __restrict__ ssz) {
    if (blockIdx.x < 64) ssz[blockIdx.x * 256 + threadIdx.x] = 0.f;
    int idx = blockIdx.x * 256 + threadIdx.x;   // 278528 units
    if (idx < 262144) {
        int n = idx >> 8;
        int so = (idx & 255) * 4;
        int k0 = (so & ~63) | ((((so >> 3) & 7) ^ (n & 7)) << 3) | (so & 7);
        ushort po[4];
#pragma unroll
        for (int u = 0; u < 4; ++u) {
            int kk = k0 + u;
            int a = min(n, kk), b = max(n, kk);
            int tm = a >> 7, tn = b >> 7;
            int tlin = tm * 8 - ((tm * (tm - 1)) >> 1) + (tn - tm);
            size_t off = (size_t)tlin * 16384 + (size_t)(a & 127) * 128 + (b & 127);
            po[u] = (ushort)(Gsum[off] ^ 0x8000u);   // negate via sign bit
        }
        ushort4 o; o.x = po[0]; o.y = po[1]; o.z = po[2]; o.w = po[3];
        *(ushort4*)(Gb + (size_t)n * DIM + so) = o;
    } else {
        int vv = idx - 262144;                  // 16384 units
        int d = vv >> 4;
        int so = (vv & 15) * 4;
        int k0 = ((((so >> 3) & 7) ^ (d & 7)) << 3) | (so & 7);
        const ushort* src = PXsum + (size_t)d * OUTD + k0;
        ushort4 o; o.x = src[0]; o.y = src[1]; o.z = src[2]; o.w = src[3];
        *(ushort4*)(PtXTb + (size_t)d * OUTD + so) = o;
    }
}

// ---------------------------------------------------------------------------
// NT MFMA GEMM body (R5-proven, byte-identical math to R10). Non-TRI: m0 =
// bx*BM, n0 = by*BN, zidx = bz. TRI: bx is flat; nz==16 -> R7 mapping
// (8*36*2, zidx=(bid&7)|(zhi<<3)); nz==4 -> 36*4. Upper-tri 128x128 tiles.
// EPI 0: plain bf16 pair-stores into per-z partial buffer.
// EPI 1: seg0 acc scaled by 1/sqrt(ssrd[m]); writes bf16 master + row
//        sum-of-squares atomics into ssacc.
template<int BM, int BN, int EPI, int TRI>
__device__ __forceinline__ void gemm_body(
        const ushort* __restrict__ A0, int lda0,
        const ushort* __restrict__ B0, int ldb0, int k0len,
        const ushort* __restrict__ A1, int lda1,
        const ushort* __restrict__ B1, int ldb1, int k1len,
        float* __restrict__ C, int ldc,
        const float* __restrict__ ssrd, float gamma,
        float* __restrict__ ssacc, int pstride, int nz,
        int bx, int by, int bz, ushort* ls) {
    constexpr int WTN = BN / 2;
    constexpr int NF = WTN / 16;
    constexpr int NAW = BM / 64;     // waves staging A
    constexpr int NBW = BN / 64;     // waves staging B
    ushort* lsA = ls;
    ushort* lsB = ls + BM * 64;
    int t = threadIdx.x;
    int wave = t >> 6, lane = t & 63;
    int rl = lane & 15, q = lane >> 4;
    int wm = wave & 1, wn = wave >> 1;
    int m0, n0, zidx, tlin = 0;
    if (TRI) {
        int bid = bx;
        int bxx, tm = 0;
        if (nz == 16) {                 // R7-proven mapping: grid 8*36*2
            int rest = bid >> 3;
            bxx = rest % 36;
            int zhi = rest / 36;
            zidx = (bid & 7) | (zhi << 3);
        } else {                        // fallback: grid 36*4
            zidx = bid & 3;
            bxx = bid >> 2;
        }
        tlin = bxx;
        while (bxx >= 8 - tm) { bxx -= 8 - tm; ++tm; }
        m0 = tm * 128; n0 = (tm + bxx) * 128;
    } else {
        m0 = bx * BM; n0 = by * BN; zidx = bz;
    }
    int lrow8 = lane >> 3, lgrp = lane & 7;
    bool isA = wave < NAW;
    bool active = wave < NAW + NBW;
    int wlocal = isA ? wave : wave - NAW;
    ushort* dstb = ls + (isA ? 0 : BM * 64) + wlocal * 4096;

    f32x4 acc[4][NF];
#pragma unroll
    for (int i = 0; i < 4; ++i)
#pragma unroll
        for (int j = 0; j < NF; ++j) acc[i][j] = f32x4{0.f, 0.f, 0.f, 0.f};
    float rvv[4][4];

    for (int seg = 0; seg < 2; ++seg) {
        int klen = seg ? k1len : k0len;
        if (klen > 0) {
            const ushort* OPA = seg ? A1 : A0;
            const ushort* OPB = seg ? B1 : B0;
            int ldaS = seg ? lda1 : lda0;
            int ldbS = seg ? ldb1 : ldb0;
            int kb = seg ? 0 : zidx * k0len;
            const ushort* srcb;
            size_t ldS;
            if (isA) {
                srcb = OPA + (size_t)(m0 + wlocal * 64 + lrow8) * ldaS + lgrp * 8;
                ldS = (size_t)ldaS;
            } else {
                srcb = OPB + (size_t)(n0 + wlocal * 64 + lrow8) * ldbS + lgrp * 8;
                ldS = (size_t)ldbS;
            }
            srcb += kb;
            for (int kt = 0; kt < klen; kt += 64) {
                if (active) {
#pragma unroll
                    for (int c = 0; c < 8; ++c)
                        __builtin_amdgcn_global_load_lds(AS1C(srcb + c * 8 * ldS),
                                                         AS3(dstb + c * 512), 16, 0, 0);
                    srcb += 64;
                }
                __syncthreads();
#pragma unroll
                for (int s = 0; s < 2; ++s) {
                    bf16x8 af[4], bfr[NF];
#pragma unroll
                    for (int i = 0; i < 4; ++i) {
                        int row = wm * 64 + i * 16 + rl;
                        int sg = ((s << 2) | q) ^ (row & 7);
                        af[i] = *(const bf16x8*)&lsA[row * 64 + sg * 8];
                    }
#pragma unroll
                    for (int j = 0; j < NF; ++j) {
                        int row = wn * WTN + j * 16 + rl;
                        int sg = ((s << 2) | q) ^ (row & 7);
                        bfr[j] = *(const bf16x8*)&lsB[row * 64 + sg * 8];
                    }
#pragma unroll
                    for (int i = 0; i < 4; ++i)
#pragma unroll
                        for (int j = 0; j < NF; ++j)
                            acc[i][j] = __builtin_amdgcn_mfma_f32_16x16x32_bf16(
                                af[i], bfr[j], acc[i][j], 0, 0, 0);
                }
                __syncthreads();
            }
        }
        if (EPI == 1 && seg == 0) {
#pragma unroll
            for (int i = 0; i < 4; ++i)
#pragma unroll
                for (int rg = 0; rg < 4; ++rg)
                    rvv[i][rg] = 1.0f / sqrtf(ssrd[m0 + wm * 64 + i * 16 + q * 4 + rg]);
#pragma unroll
            for (int i = 0; i < 4; ++i)
#pragma unroll
                for (int j = 0; j < NF; ++j)
#pragma unroll
                    for (int rg = 0; rg < 4; ++rg)
                        acc[i][j][rg] *= rvv[i][rg];
        }
    }

    if (EPI == 0) {
        // plain bf16 pair stores into this z-slice's partial buffer
        ushort* Cb = (ushort*)C + (size_t)zidx * (size_t)pstride;
#pragma unroll
        for (int i = 0; i < 4; ++i)
#pragma unroll
            for (int j = 0; j < NF; ++j)
#pragma unroll
                for (int rg = 0; rg < 4; ++rg) {
                    float v = acc[i][j][rg];
                    float vp = __shfl_xor(v, 1);   // partner lane's (n^1) value
                    if ((rl & 1) == 0) {
                        int ml = wm * 64 + i * 16 + q * 4 + rg;
                        int nl = wn * WTN + j * 16 + rl;
                        size_t off;
                        if (TRI)
                            off = (size_t)tlin * (BM * BN) + (size_t)ml * BN + nl;
                        else
                            off = (size_t)(m0 + ml) * ldc + (n0 + nl);
                        unsigned pk = (unsigned)f2bf(v) | ((unsigned)f2bf(vp) << 16);
                        *(unsigned*)(Cb + off) = pk;
                    }
                }
    } else {
#pragma unroll
        for (int i = 0; i < 4; ++i)
#pragma unroll
            for (int rg = 0; rg < 4; ++rg) {
                int m = m0 + wm * 64 + i * 16 + q * 4 + rg;
                float ssl = 0.f;
#pragma unroll
                for (int j = 0; j < NF; ++j) {
                    int n = n0 + wn * WTN + j * 16 + rl;
                    int so = swz(n, m);
                    float base = b2f(A0[(size_t)m * lda0 + so]);
                    float vf = base * rvv[i][rg] + gamma * acc[i][j][rg];
                    ((ushort*)C)[(size_t)m * ldc + so] = f2bf(vf);
                    ssl += vf * vf;
                }
                ssl += __shfl_xor(ssl, 1);
                ssl += __shfl_xor(ssl, 2);
                ssl += __shfl_xor(ssl, 4);
                ssl += __shfl_xor(ssl, 8);
                if (rl == 0) atomicAdd(&ssacc[m], ssl);
            }
    }
}

template<int BM, int BN, int EPI, int TRI>
__global__ __launch_bounds__(256, 3) void gemm_nt_k(
        const ushort* __restrict__ A0, int lda0,
        const ushort* __restrict__ B0, int ldb0, int k0len,
        const ushort* __restrict__ A1, int lda1,
        const ushort* __restrict__ B1, int ldb1, int k1len,
        float* __restrict__ C, int ldc,
        const float* __restrict__ ssrd, float gamma,
        float* __restrict__ ssacc, int pstride, int nz) {
    __shared__ ushort ls[(BM + BN) * 64];
    gemm_body<BM, BN, EPI, TRI>(A0, lda0, B0, ldb0, k0len, A1, lda1, B1, ldb1,
        k1len, C, ldc, ssrd, gamma, ssacc, pstride, nz,
        blockIdx.x, blockIdx.y, blockIdx.z, ls);
}

// ---------------------------------------------------------------------------
// Fused G-gemm (blocks 0..575, TRI split-K 16, R7 XCD-affine mapping) +
// PtX-gemm (blocks 576..831, split-K 32). Independent: both read XnT (+PTb),
// write disjoint partial buffers.
__global__ __launch_bounds__(256, 3) void gp_k(const ushort* __restrict__ XnT,
        const ushort* __restrict__ PTb, ushort* __restrict__ Gpart,
        ushort* __restrict__ PXpart) {
    __shared__ ushort ls[256 * 64];
    int bid = blockIdx.x;
    if (bid < 576) {
        gemm_body<128, 128, 0, 1>(XnT, N_ROWS, XnT, N_ROWS, 1024,
            nullptr, 0, nullptr, 0, 0,
            (float*)Gpart, 128, nullptr, 0.f, nullptr, 36 * 16384, 16,
            bid, 0, 0, ls);
    } else {
        int b2 = bid - 576;
        gemm_body<128, 64, 0, 0>(XnT, N_ROWS, PTb, N_ROWS, 512,
            nullptr, 0, nullptr, 0, 0,
            (float*)PXpart, OUTD, nullptr, 0.f, nullptr, DIM * OUTD, 0,
            b2 & 7, 0, b2 >> 3, ls);
    }
}

// ---------------------------------------------------------------------------
extern "C" void kernel_launch(void* const* d_in, const int* in_sizes, int n_in,
                              void* d_out, int out_size, void* d_ws, size_t ws_size,
                              hipStream_t stream) {
    const float* X = (const float*)d_in[0];
    const float* W1 = (const float*)d_in[1];
    const float* b1 = (const float*)d_in[2];
    const float* W2 = (const float*)d_in[3];
    const float* b2 = (const float*)d_in[4];
    float* out = (float*)d_out;
    char* ws = (char*)d_ws;

    constexpr size_t O_BufA    = 0;                                     // 33,554,432
    constexpr size_t O_BufB    = O_BufA + (size_t)N_ROWS * DIM * 2;     // 33,554,432
    constexpr size_t O_Pb      = O_BufB + (size_t)N_ROWS * DIM * 2;     //  2,097,152
    constexpr size_t O_PTb     = O_Pb + (size_t)N_ROWS * OUTD * 2;      //  2,097,152
    constexpr size_t O_Gb      = O_PTb + (size_t)OUTD * N_ROWS * 2;     //  2,097,152
    constexpr size_t O_PtXTb   = O_Gb + (size_t)DIM * DIM * 2;          //    131,072
    constexpr size_t O_ssB     = O_PtXTb + (size_t)DIM * OUTD * 2;      //     65,536 (old riv slot)
    constexpr size_t O_W1T     = O_ssB + (size_t)N_ROWS * 4;            //     32,768
    constexpr size_t O_ssA     = O_W1T + (size_t)HID * DIM * 2;         //     65,536
    constexpr size_t O_scratch = O_ssA + (size_t)N_ROWS * 4;            // = 73,695,232
    // scratch time-shares: z (1,048,576 f32, live txz->head) and Gpart
    // (big: 16 x 589824 x 2 = 18,874,368 -> ws end 92,569,600;
    //  small: 4 x 589824 x 2). PXpart in d_out (4MB, dead until final head).
    // Gsum+PXsum live in the PTb region (dead between gp_k and next head_k).
    constexpr size_t WS_BIG = O_scratch + (size_t)16 * 589824 * 2;

    ushort* bufA  = (ushort*)(ws + O_BufA);
    ushort* bufB  = (ushort*)(ws + O_BufB);
    ushort* Pb    = (ushort*)(ws + O_Pb);
    ushort* PTb   = (ushort*)(ws + O_PTb);
    ushort* Gb    = (ushort*)(ws + O_Gb);
    ushort* PtXTb = (ushort*)(ws + O_PtXTb);
    float*  ssB   = (float*)(ws + O_ssB);
    ushort* W1T   = (ushort*)(ws + O_W1T);
    float*  ssA   = (float*)(ws + O_ssA);
    float*  z     = (float*)(ws + O_scratch);
    ushort* Gpart = (ushort*)(ws + O_scratch);
    ushort* PXpart = (ushort*)d_out;
    ushort* Gsum  = PTb;                       // PTb region reuse (dead)
    ushort* PXsum = PTb + 589824;
    (void)in_sizes; (void)n_in; (void)out_size;

    const bool big = ws_size >= WS_BIG;
    const int nzg = big ? 16 : 4;
    const int nzp = big ? 32 : 8;

    prep_w1t_k<<<64, 256, 0, stream>>>(W1, W1T);
    tobf16_k<<<N_ROWS, 256, 0, stream>>>(X, bufA, ssA);

    ushort* xm  = bufA;   // current master X_t (bf16, swizzled rows)
    ushort* alt = bufB;   // scratch: XnT during iter, then becomes X_{t+1}
    float* ssCur = ssA;   // ||X_t||^2 per row
    float* ssNxt = ssB;

    for (int it = 0; it < DEPTH; ++it) {
        if (big) {
            // fused transpose + zgemm (independent subgraphs, one grid)
            txz_k<<<4096 + 256, 256, 0, stream>>>(xm, ssCur, alt, W1T, b1, z);
        } else {
            transpose_k<<<dim3(N_ROWS / 64, DIM / 64), 256, 0, stream>>>(xm, ssCur, alt);
            zgemm_k<<<N_ROWS / 64, 256, 0, stream>>>(xm, W1T, b1, z, ssCur);
        }
        head_k<<<N_ROWS / 256, 256, 0, stream>>>(z, W2, b2, Pb, PTb, nullptr, 1);
        if (big) {
            // fused G (576, XCD-affine split-K 16) + PtX (256, split-K 32)
            gp_k<<<576 + 256, 256, 0, stream>>>(alt, PTb, Gpart, PXpart);
        } else {
            gemm_nt_k<128, 128, 0, 1><<<dim3(36 * 4, 1, 1), 256, 0, stream>>>(
                alt, N_ROWS, alt, N_ROWS, 4096,
                nullptr, 0, nullptr, 0, 0,
                (float*)Gpart, 128, nullptr, 0.f, nullptr, 36 * 16384, 4);
            gemm_nt_k<128, 64, 0, 0><<<dim3(8, 1, 8), 256, 0, stream>>>(
                alt, N_ROWS, PTb, N_ROWS, 2048,
                nullptr, 0, nullptr, 0, 0,
                (float*)PXpart, OUTD, nullptr, 0.f, nullptr, DIM * OUTD, 0);
        }
        // Pass A: coalesced z-reduction into compact sums (PTb now dead)
        reduce_k<<<320, 256, 0, stream>>>(Gpart, PXpart, Gsum, PXsum, nzg, nzp);
        // Pass B: gather/mirror/swizzle of the L2-resident sums + zero ssNxt
        castgp_k<<<1088, 256, 0, stream>>>(Gsum, PXsum, Gb, PtXTb, ssNxt);
        // X_{t+1} = Xn + g*(P@PtX - Xn@G); writes `alt`; accumulates ssNxt
        gemm_nt_k<128, 128, 1, 0><<<dim3(N_ROWS / 128, DIM / 128, 1), 256, 0, stream>>>(
            xm, DIM, Gb, DIM, 1024,
            Pb, OUTD, PtXTb, OUTD, OUTD,
            (float*)alt, DIM, ssCur, GAMMA, ssNxt, 0, 0);
        ushort* tmp = xm; xm = alt; alt = tmp;   // ping-pong
        float* ts2 = ssCur; ssCur = ssNxt; ssNxt = ts2;
    }

    // final: out = relu(X@W1 + b1) @ W2 + b2  (unnormalized master, ss=nullptr)
    zgemm_k<<<N_ROWS / 64, 256, 0, stream>>>(xm, W1T, b1, z, nullptr);
    head_k<<<N_ROWS / 256, 256, 0, stream>>>(z, W2, b2, Pb, PTb, out, 0);
}